// Round 1
// baseline (2302.897 us; speedup 1.0000x reference)
//
#include <hip/hip_runtime.h>
#include <math.h>

#define EPSV 1e-5f

// =============================== GEMM ===================================
// C[M,N] = A[M,K] @ B[K,N] (+bias) ; TRANSB=1 means B is [N,K] row-major.
// 128x128 tile, BK=16, 256 threads, 8x8 per-thread micro-tile.
// LDS tiles stored k-major so fragments load as float4 (ds_read_b128).
template<int TRANSB>
__global__ __launch_bounds__(256) void gemm128(
    const float* __restrict__ A, const float* __restrict__ B,
    const float* __restrict__ bias, float* __restrict__ C,
    int M, int N, int K, int lda, int ldb, int ldc,
    long aH, long bH, long cH)
{
    const int tid = threadIdx.x;
    const int tx = tid & 15, ty = tid >> 4;
    A += (long)blockIdx.z * aH;
    B += (long)blockIdx.z * bH;
    C += (long)blockIdx.z * cH;
    const int bm = blockIdx.y * 128, bn = blockIdx.x * 128;

    __shared__ float As[16][132];
    __shared__ float Bs[16][132];

    float acc[8][8];
    #pragma unroll
    for (int i = 0; i < 8; i++)
        #pragma unroll
        for (int j = 0; j < 8; j++) acc[i][j] = 0.f;

    const int lr = tid >> 2;        // 0..63
    const int lc = (tid & 3) * 4;   // 0,4,8,12

    for (int k0 = 0; k0 < K; k0 += 16) {
        float4 a0 = *(const float4*)&A[(long)(bm + lr) * lda + k0 + lc];
        float4 a1 = *(const float4*)&A[(long)(bm + lr + 64) * lda + k0 + lc];
        float4 b0, b1;
        if (TRANSB) {
            b0 = *(const float4*)&B[(long)(bn + lr) * ldb + k0 + lc];
            b1 = *(const float4*)&B[(long)(bn + lr + 64) * ldb + k0 + lc];
        } else {
            b0 = *(const float4*)&B[(long)(k0 + (tid >> 5)) * ldb + bn + (tid & 31) * 4];
            b1 = *(const float4*)&B[(long)(k0 + (tid >> 5) + 8) * ldb + bn + (tid & 31) * 4];
        }
        __syncthreads();   // previous iteration's compute done before overwrite
        As[lc + 0][lr] = a0.x; As[lc + 1][lr] = a0.y;
        As[lc + 2][lr] = a0.z; As[lc + 3][lr] = a0.w;
        As[lc + 0][lr + 64] = a1.x; As[lc + 1][lr + 64] = a1.y;
        As[lc + 2][lr + 64] = a1.z; As[lc + 3][lr + 64] = a1.w;
        if (TRANSB) {
            Bs[lc + 0][lr] = b0.x; Bs[lc + 1][lr] = b0.y;
            Bs[lc + 2][lr] = b0.z; Bs[lc + 3][lr] = b0.w;
            Bs[lc + 0][lr + 64] = b1.x; Bs[lc + 1][lr + 64] = b1.y;
            Bs[lc + 2][lr + 64] = b1.z; Bs[lc + 3][lr + 64] = b1.w;
        } else {
            *(float4*)&Bs[tid >> 5][(tid & 31) * 4] = b0;
            *(float4*)&Bs[(tid >> 5) + 8][(tid & 31) * 4] = b1;
        }
        __syncthreads();
        #pragma unroll
        for (int k = 0; k < 16; k++) {
            float av[8], bv[8];
            *(float4*)&av[0] = *(const float4*)&As[k][ty * 4];
            *(float4*)&av[4] = *(const float4*)&As[k][ty * 4 + 64];
            *(float4*)&bv[0] = *(const float4*)&Bs[k][tx * 4];
            *(float4*)&bv[4] = *(const float4*)&Bs[k][tx * 4 + 64];
            #pragma unroll
            for (int i = 0; i < 8; i++)
                #pragma unroll
                for (int j = 0; j < 8; j++)
                    acc[i][j] = fmaf(av[i], bv[j], acc[i][j]);
        }
    }
    #pragma unroll
    for (int ih = 0; ih < 2; ih++)
        #pragma unroll
        for (int ii = 0; ii < 4; ii++) {
            int r = bm + ty * 4 + ii + ih * 64;
            #pragma unroll
            for (int jh = 0; jh < 2; jh++) {
                int cc = bn + tx * 4 + jh * 64;
                float4 v;
                v.x = acc[ih*4+ii][jh*4+0]; v.y = acc[ih*4+ii][jh*4+1];
                v.z = acc[ih*4+ii][jh*4+2]; v.w = acc[ih*4+ii][jh*4+3];
                if (bias) { v.x += bias[cc]; v.y += bias[cc+1]; v.z += bias[cc+2]; v.w += bias[cc+3]; }
                *(float4*)&C[(long)r * ldc + cc] = v;
            }
        }
}

// ============================ helpers ===================================
__global__ void transpose1024(const float* __restrict__ in, float* __restrict__ out)
{
    __shared__ float t[32][33];
    int bx = blockIdx.x * 32, by = blockIdx.y * 32;
    #pragma unroll
    for (int i = 0; i < 32; i += 8)
        t[threadIdx.y + i][threadIdx.x] = in[(long)(by + threadIdx.y + i) * 1024 + bx + threadIdx.x];
    __syncthreads();
    #pragma unroll
    for (int i = 0; i < 32; i += 8)
        out[(long)(bx + threadIdx.y + i) * 1024 + by + threadIdx.x] = t[threadIdx.x][threadIdx.y + i];
}

// qe[c,h] = q[c, h*Cd : (h+1)*Cd] . ew[h*Cd : ...]  (one wave per (c,h))
__global__ __launch_bounds__(256) void compute_qe(
    const float* __restrict__ q, const float* __restrict__ ew,
    float* __restrict__ qe, int H, int Cd, int F)
{
    int gw = (blockIdx.x * 256 + threadIdx.x) >> 6;
    int lane = threadIdx.x & 63;
    int c = gw / H, h = gw % H;
    const float* qr = q + (long)c * F + h * Cd;
    const float* w  = ew + h * Cd;
    float s = 0.f;
    for (int d = lane; d < Cd; d += 64) s += qr[d] * w[d];
    #pragma unroll
    for (int o = 32; o; o >>= 1) s += __shfl_xor(s, o);
    if (lane == 0) qe[c * H + h] = s;
}

// Row softmax over sources r with edge term; also aw[c,h] = sum alpha * x[r,c]
__global__ __launch_bounds__(256) void softmax_edge(
    float* __restrict__ S, const float* __restrict__ xT,
    const float* __restrict__ qe, float* __restrict__ aw,
    int H, float inv_sqrt_d)
{
    const int c = blockIdx.x, h = blockIdx.y, tid = threadIdx.x;
    float* row = S + ((long)h * 1024 + c) * 1024;
    const float* xc = xT + (long)c * 1024;
    const float qeh = qe[c * H + h] * inv_sqrt_d;
    float l[4], xv[4];
    float mx = -1e30f;
    #pragma unroll
    for (int i = 0; i < 4; i++) {
        int r = tid + i * 256;
        xv[i] = xc[r];
        l[i] = row[r] * inv_sqrt_d + xv[i] * qeh;
        mx = fmaxf(mx, l[i]);
    }
    __shared__ float red[8];
    #pragma unroll
    for (int o = 32; o; o >>= 1) mx = fmaxf(mx, __shfl_xor(mx, o));
    if ((tid & 63) == 0) red[tid >> 6] = mx;
    __syncthreads();
    mx = fmaxf(fmaxf(red[0], red[1]), fmaxf(red[2], red[3]));
    __syncthreads();
    float e[4], se = 0.f, sa = 0.f;
    #pragma unroll
    for (int i = 0; i < 4; i++) {
        e[i] = __expf(l[i] - mx);
        se += e[i];
        sa += e[i] * xv[i];
    }
    #pragma unroll
    for (int o = 32; o; o >>= 1) { se += __shfl_xor(se, o); sa += __shfl_xor(sa, o); }
    if ((tid & 63) == 0) { red[tid >> 6] = se; red[4 + (tid >> 6)] = sa; }
    __syncthreads();
    se = red[0] + red[1] + red[2] + red[3];
    sa = red[4] + red[5] + red[6] + red[7];
    float inv = 1.f / se;
    #pragma unroll
    for (int i = 0; i < 4; i++) row[tid + i * 256] = e[i] * inv;
    if (tid == 0) aw[c * H + h] = sa * inv;
}

// out += skip + aw[c,h]*ew[f]   (float4 elementwise)
__global__ void combine_kernel(float* __restrict__ out, const float* __restrict__ skip,
    const float* __restrict__ aw, const float* __restrict__ ew, int F, int Cd, int H)
{
    long idx = ((long)blockIdx.x * 256 + threadIdx.x) * 4;
    int c = (int)(idx / F), f = (int)(idx % F);
    int h = f / Cd;
    float a = aw[c * H + h];
    float4 o = *(float4*)&out[idx];
    float4 s = *(const float4*)&skip[idx];
    float4 w = *(const float4*)&ew[f];
    o.x += s.x + a * w.x; o.y += s.y + a * w.y;
    o.z += s.z + a * w.z; o.w += s.w + a * w.w;
    *(float4*)&out[idx] = o;
}

// GraphNorm: column stats in two stages, then apply
__global__ void col_stats1(const float* __restrict__ X, float* __restrict__ ps,
                           float* __restrict__ ps2, int F)
{
    int f = blockIdx.x * 256 + threadIdx.x;
    int r0 = blockIdx.y * 32;
    float s = 0.f, s2 = 0.f;
    for (int r = r0; r < r0 + 32; r++) {
        float v = X[(long)r * F + f];
        s += v; s2 += v * v;
    }
    ps [(long)blockIdx.y * F + f] = s;
    ps2[(long)blockIdx.y * F + f] = s2;
}

__global__ void col_stats2(const float* __restrict__ ps, const float* __restrict__ ps2,
    const float* __restrict__ ms, float* __restrict__ msmu, float* __restrict__ rs, int F)
{
    int f = blockIdx.x * 256 + threadIdx.x;
    float s = 0.f, s2 = 0.f;
    for (int ch = 0; ch < 32; ch++) { s += ps[(long)ch * F + f]; s2 += ps2[(long)ch * F + f]; }
    float m  = s  * (1.f / 1024.f);
    float m2 = s2 * (1.f / 1024.f);
    float a = ms[f] * m;                 // ms*mu
    msmu[f] = a;
    float var = m2 - 2.f * a * m + a * a;  // E[(x-a)^2]
    rs[f] = rsqrtf(var + EPSV);
}

__global__ void gnorm_apply(float* __restrict__ X, const float* __restrict__ msmu,
    const float* __restrict__ rs, const float* __restrict__ g, const float* __restrict__ b, int F)
{
    long idx = ((long)blockIdx.x * 256 + threadIdx.x) * 4;
    int f = (int)(idx % F);
    float4 v = *(float4*)&X[idx];
    v.x = g[f+0] * (v.x - msmu[f+0]) * rs[f+0] + b[f+0];
    v.y = g[f+1] * (v.y - msmu[f+1]) * rs[f+1] + b[f+1];
    v.z = g[f+2] * (v.z - msmu[f+2]) * rs[f+2] + b[f+2];
    v.w = g[f+3] * (v.w - msmu[f+3]) * rs[f+3] + b[f+3];
    *(float4*)&X[idx] = v;
}

__global__ __launch_bounds__(256) void l2norm_rows(float* __restrict__ X, int F)
{
    const int r = blockIdx.x, tid = threadIdx.x;
    float* row = X + (long)r * F;
    float s = 0.f;
    for (int f = tid * 4; f < F; f += 1024) {
        float4 v = *(const float4*)&row[f];
        s += v.x*v.x + v.y*v.y + v.z*v.z + v.w*v.w;
    }
    __shared__ float red[4];
    #pragma unroll
    for (int o = 32; o; o >>= 1) s += __shfl_xor(s, o);
    if ((tid & 63) == 0) red[tid >> 6] = s;
    __syncthreads();
    s = red[0] + red[1] + red[2] + red[3];
    float inv = rsqrtf(s);
    for (int f = tid * 4; f < F; f += 1024) {
        float4 v = *(const float4*)&row[f];
        v.x *= inv; v.y *= inv; v.z *= inv; v.w *= inv;
        *(float4*)&row[f] = v;
    }
}

// ============================ host side =================================
static inline void gemm(hipStream_t st, const float* A, const float* B, const float* bias,
                        float* C, int M, int N, int K, int lda, int ldb, int ldc,
                        int nz, long aH, long bH, long cH, bool transB)
{
    dim3 g(N / 128, M / 128, nz), b(256);
    if (transB) gemm128<1><<<g, b, 0, st>>>(A, B, bias, C, M, N, K, lda, ldb, ldc, aH, bH, cH);
    else        gemm128<0><<<g, b, 0, st>>>(A, B, bias, C, M, N, K, lda, ldb, ldc, aH, bH, cH);
}

static void conv_layer(hipStream_t st, const float* xin, int Fin,
                       const float* qw, const float* qb, const float* kw, const float* kb,
                       const float* vw, const float* vb, const float* ew,
                       const float* sw, const float* sb,
                       int H, int Cd, float* out,
                       float* q, float* k, float* v, float* skip, float* S,
                       float* qe, float* aw, const float* xT)
{
    const int n = 1024, F = H * Cd;
    gemm(st, xin, qw, qb, q,    n, F, Fin, Fin, F, F, 1, 0, 0, 0, false);
    gemm(st, xin, kw, kb, k,    n, F, Fin, Fin, F, F, 1, 0, 0, 0, false);
    gemm(st, xin, vw, vb, v,    n, F, Fin, Fin, F, F, 1, 0, 0, 0, false);
    gemm(st, xin, sw, sb, skip, n, F, Fin, Fin, F, F, 1, 0, 0, 0, false);

    compute_qe<<<(n * H) / 4, 256, 0, st>>>(q, ew, qe, H, Cd, F);

    // S[h] = Q_h @ K_h^T
    gemm(st, q, k, nullptr, S, n, n, Cd, F, F, n, H, (long)Cd, (long)Cd, (long)n * n, true);

    float inv_sqrt_d = 1.0f / sqrtf((float)Cd);
    dim3 sg(n, H);
    softmax_edge<<<sg, 256, 0, st>>>(S, xT, qe, aw, H, inv_sqrt_d);

    // out[h] = alpha_h @ V_h
    gemm(st, S, v, nullptr, out, n, Cd, n, n, F, F, H, (long)n * n, (long)Cd, (long)Cd, false);

    long tot4 = (long)n * F / 4;
    combine_kernel<<<(int)(tot4 / 256), 256, 0, st>>>(out, skip, aw, ew, F, Cd, H);
}

static void gnorm(hipStream_t st, float* X, int F, const float* gamma, const float* beta,
                  const float* ms, float* ps, float* ps2, float* msmu, float* rs)
{
    dim3 g1(F / 256, 32);
    col_stats1<<<g1, 256, 0, st>>>(X, ps, ps2, F);
    col_stats2<<<F / 256, 256, 0, st>>>(ps, ps2, ms, msmu, rs, F);
    long tot4 = (long)1024 * F / 4;
    gnorm_apply<<<(int)(tot4 / 256), 256, 0, st>>>(X, msmu, rs, gamma, beta, F);
}

extern "C" void kernel_launch(void* const* d_in, const int* in_sizes, int n_in,
                              void* d_out, int out_size, void* d_ws, size_t ws_size,
                              hipStream_t stream)
{
    const float* x    = (const float*)d_in[0];
    const float* q1w  = (const float*)d_in[1];  const float* q1b = (const float*)d_in[2];
    const float* k1w  = (const float*)d_in[3];  const float* k1b = (const float*)d_in[4];
    const float* v1w  = (const float*)d_in[5];  const float* v1b = (const float*)d_in[6];
    const float* e1w  = (const float*)d_in[7];
    const float* s1w  = (const float*)d_in[8];  const float* s1b = (const float*)d_in[9];
    const float* gn1g = (const float*)d_in[10]; const float* gn1b = (const float*)d_in[11];
    const float* gn1ms= (const float*)d_in[12];
    const float* q2w  = (const float*)d_in[13]; const float* q2b = (const float*)d_in[14];
    const float* k2w  = (const float*)d_in[15]; const float* k2b = (const float*)d_in[16];
    const float* v2w  = (const float*)d_in[17]; const float* v2b = (const float*)d_in[18];
    const float* e2w  = (const float*)d_in[19];
    const float* s2w  = (const float*)d_in[20]; const float* s2b = (const float*)d_in[21];
    const float* gn2g = (const float*)d_in[22]; const float* gn2b = (const float*)d_in[23];
    const float* gn2ms= (const float*)d_in[24];
    float* out = (float*)d_out;

    float* W = (float*)d_ws;
    float* xT   = W; W += (long)1024 * 1024;
    float* q    = W; W += (long)1024 * 4096;
    float* kbuf = W; W += (long)1024 * 4096;
    float* vbuf = W; W += (long)1024 * 4096;
    float* skip = W; W += (long)1024 * 4096;
    float* S    = W; W += (long)8 * 1024 * 1024;
    float* h1   = W; W += (long)1024 * 2048;
    float* qe   = W; W += 8192;
    float* aw   = W; W += 8192;
    float* ps   = W; W += 32 * 4096;
    float* ps2  = W; W += 32 * 4096;
    float* msmu = W; W += 4096;
    float* rs   = W; W += 4096;

    transpose1024<<<dim3(32, 32), dim3(32, 8), 0, stream>>>(x, xT);

    // Layer 1: H=4, Cd=512, Fin=1024, Fout=2048
    conv_layer(stream, x, 1024, q1w, q1b, k1w, k1b, v1w, v1b, e1w, s1w, s1b,
               4, 512, h1, q, kbuf, vbuf, skip, S, qe, aw, xT);
    gnorm(stream, h1, 2048, gn1g, gn1b, gn1ms, ps, ps2, msmu, rs);

    // Layer 2: H=8, Cd=512, Fin=2048, Fout=4096 -> straight into d_out
    conv_layer(stream, h1, 2048, q2w, q2b, k2w, k2b, v2w, v2b, e2w, s2w, s2b,
               8, 512, out, q, kbuf, vbuf, skip, S, qe, aw, xT);
    gnorm(stream, out, 4096, gn2g, gn2b, gn2ms, ps, ps2, msmu, rs);

    l2norm_rows<<<1024, 256, 0, stream>>>(out, 4096);
}

// Round 2
// 585.691 us; speedup vs baseline: 3.9319x; 3.9319x over previous
//
#include <hip/hip_runtime.h>
#include <math.h>

#define EPSV 1e-5f

typedef __attribute__((ext_vector_type(8))) short bf16x8;
typedef __attribute__((ext_vector_type(4))) float f32x4;

__device__ __forceinline__ unsigned short f2bf(float f) {
    unsigned int u = __float_as_uint(f);
    return (unsigned short)((u + 0x7fffu + ((u >> 16) & 1u)) >> 16);
}
__device__ __forceinline__ float b2f(unsigned short u) {
    return __uint_as_float(((unsigned int)u) << 16);
}

__device__ __forceinline__ void glds16(const unsigned short* g, unsigned short* l) {
    __builtin_amdgcn_global_load_lds(
        (const __attribute__((address_space(1))) void*)g,
        (__attribute__((address_space(3))) void*)l, 16, 0, 0);
}

// ====================== bf16 MFMA GEMM (B^T layout) ======================
// C[M,N] = A[M,K] * B[N,K]^T (+bias).  A,B bf16 row-major with K innermost.
// 128x128 tile, BK=32, 256 threads = 4 waves, each wave 64x64 (4x4 frags of
// 16x16x32 MFMA).  global_load_lds width-16 staging, m97 2-barrier loop.
template<int BIAS, int OUTBF>
__global__ __launch_bounds__(256) void gemm_bt(
    const unsigned short* __restrict__ A, const unsigned short* __restrict__ B,
    const float* __restrict__ bias, void* __restrict__ Cout,
    int K, int lda, int ldb, int ldc,
    long aH, long bH, long cH)
{
    __shared__ unsigned short As[4096];
    __shared__ unsigned short Bs[4096];
    const int tid = threadIdx.x;
    const int wid = tid >> 6, lane = tid & 63;
    const int bm = blockIdx.y * 128, bn = blockIdx.x * 128;
    A += (long)blockIdx.z * aH;
    B += (long)blockIdx.z * bH;

    const int wr = wid >> 1, wc = wid & 1;

    // staging: wave w fills 1KB chunks w and w+4 of each tile
    const int r0 = (wid << 4) + (lane >> 2);   // row in tile (0..63), +64 for 2nd chunk
    const int kq = (lane & 3) << 3;            // k offset in elements (0,8,16,24)
    const unsigned short* gA0 = A + (long)(bm + r0) * lda + kq;
    const unsigned short* gA1 = gA0 + (long)64 * lda;
    const unsigned short* gB0 = B + (long)(bn + r0) * ldb + kq;
    const unsigned short* gB1 = gB0 + (long)64 * ldb;
    unsigned short* lA0 = &As[wid << 9];
    unsigned short* lA1 = &As[(wid << 9) + 2048];
    unsigned short* lB0 = &Bs[wid << 9];
    unsigned short* lB1 = &Bs[(wid << 9) + 2048];

    f32x4 acc[4][4];
    #pragma unroll
    for (int m = 0; m < 4; m++)
        #pragma unroll
        for (int n = 0; n < 4; n++) acc[m][n] = (f32x4){0.f, 0.f, 0.f, 0.f};

    const int fr = lane & 15;
    const int kb = (lane >> 4) << 3;
    const unsigned short* pA = &As[(wr * 64 + fr) * 32 + kb];
    const unsigned short* pB = &Bs[(wc * 64 + fr) * 32 + kb];

    for (int k0 = 0; k0 < K; k0 += 32) {
        glds16(gA0 + k0, lA0);
        glds16(gA1 + k0, lA1);
        glds16(gB0 + k0, lB0);
        glds16(gB1 + k0, lB1);
        __syncthreads();                      // drains vmcnt, loads landed
        bf16x8 af[4], bfr[4];
        #pragma unroll
        for (int m = 0; m < 4; m++) af[m] = *(const bf16x8*)(pA + (m << 9));
        #pragma unroll
        for (int n = 0; n < 4; n++) bfr[n] = *(const bf16x8*)(pB + (n << 9));
        #pragma unroll
        for (int m = 0; m < 4; m++)
            #pragma unroll
            for (int n = 0; n < 4; n++)
                acc[m][n] = __builtin_amdgcn_mfma_f32_16x16x32_bf16(
                    af[m], bfr[n], acc[m][n], 0, 0, 0);
        __syncthreads();                      // protect LDS before next stage
    }

    // epilogue: C/D layout col=lane&15, row=(lane>>4)*4+j
    const int er = (lane >> 4) << 2;
    const int ec = lane & 15;
    if (OUTBF) {
        unsigned short* C = (unsigned short*)Cout + (long)blockIdx.z * cH;
        #pragma unroll
        for (int m = 0; m < 4; m++)
            #pragma unroll
            for (int n = 0; n < 4; n++) {
                int col = bn + wc * 64 + n * 16 + ec;
                float bv = BIAS ? bias[col] : 0.f;
                #pragma unroll
                for (int j = 0; j < 4; j++) {
                    int row = bm + wr * 64 + m * 16 + er + j;
                    C[(long)row * ldc + col] = f2bf(acc[m][n][j] + bv);
                }
            }
    } else {
        float* C = (float*)Cout + (long)blockIdx.z * cH;
        #pragma unroll
        for (int m = 0; m < 4; m++)
            #pragma unroll
            for (int n = 0; n < 4; n++) {
                int col = bn + wc * 64 + n * 16 + ec;
                #pragma unroll
                for (int j = 0; j < 4; j++) {
                    int row = bm + wr * 64 + m * 16 + er + j;
                    C[(long)row * ldc + col] = acc[m][n][j];
                }
            }
    }
}

// ============================ conversions ===============================
__global__ void f2b_kernel(const float* __restrict__ src, unsigned short* __restrict__ dst)
{
    long i = ((long)blockIdx.x * 256 + threadIdx.x) * 8;
    float4 a = *(const float4*)&src[i];
    float4 b = *(const float4*)&src[i + 4];
    unsigned short o[8] = { f2bf(a.x), f2bf(a.y), f2bf(a.z), f2bf(a.w),
                            f2bf(b.x), f2bf(b.y), f2bf(b.z), f2bf(b.w) };
    *(uint4*)&dst[i] = *(uint4*)o;
}

// src fp32 [K][F] (ld=ldsrc) -> dst bf16 [F][Kdim] (dst already row-offset)
__global__ void transpose_f2b(const float* __restrict__ src, unsigned short* __restrict__ dst,
                              int ldsrc, int Kdim)
{
    __shared__ float t[32][33];
    int f0 = blockIdx.x * 32, k0 = blockIdx.y * 32;
    int tx = threadIdx.x, ty = threadIdx.y;
    #pragma unroll
    for (int i = 0; i < 4; i++)
        t[ty + i * 8][tx] = src[(long)(k0 + ty + i * 8) * ldsrc + f0 + tx];
    __syncthreads();
    #pragma unroll
    for (int i = 0; i < 4; i++)
        dst[(long)(f0 + ty + i * 8) * Kdim + k0 + tx] = f2bf(t[tx][ty + i * 8]);
}

// V block (bf16, strided) -> VT per head: dst[h*Cd*1024 + d*1024 + r]
__global__ void transpose_b2b(const unsigned short* __restrict__ src,
                              unsigned short* __restrict__ dst, int ldsrc, int Cd)
{
    __shared__ unsigned short t[32][33];
    int h = blockIdx.z;
    int d0 = blockIdx.x * 32, r0 = blockIdx.y * 32;
    int tx = threadIdx.x, ty = threadIdx.y;
    #pragma unroll
    for (int i = 0; i < 4; i++)
        t[ty + i * 8][tx] = src[(long)(r0 + ty + i * 8) * ldsrc + h * Cd + d0 + tx];
    __syncthreads();
    #pragma unroll
    for (int i = 0; i < 4; i++)
        dst[(long)h * Cd * 1024 + (long)(d0 + ty + i * 8) * 1024 + r0 + tx] = t[tx][ty + i * 8];
}

__global__ void concat4(const float* __restrict__ a, const float* __restrict__ b,
                        const float* __restrict__ c, const float* __restrict__ d,
                        float* __restrict__ o, int F)
{
    int i = blockIdx.x * 256 + threadIdx.x;
    const float* s = (i < F) ? a : (i < 2 * F) ? b : (i < 3 * F) ? c : d;
    o[i] = s[i & (F - 1)];
}

__global__ void transpose1024(const float* __restrict__ in, float* __restrict__ out)
{
    __shared__ float t[32][33];
    int bx = blockIdx.x * 32, by = blockIdx.y * 32;
    #pragma unroll
    for (int i = 0; i < 32; i += 8)
        t[threadIdx.y + i][threadIdx.x] = in[(long)(by + threadIdx.y + i) * 1024 + bx + threadIdx.x];
    __syncthreads();
    #pragma unroll
    for (int i = 0; i < 32; i += 8)
        out[(long)(bx + threadIdx.y + i) * 1024 + by + threadIdx.x] = t[threadIdx.x][threadIdx.y + i];
}

// ====================== attention non-GEMM pieces =======================
// qe[c,h] = q_row(bf16) . ew_head(fp32)
__global__ __launch_bounds__(256) void compute_qe_b(
    const unsigned short* __restrict__ q, const float* __restrict__ ew,
    float* __restrict__ qe, int H, int Cd, int ldq)
{
    int gw = (blockIdx.x * 256 + threadIdx.x) >> 6;
    int lane = threadIdx.x & 63;
    int c = gw / H, h = gw - c * H;
    const unsigned short* qr = q + (long)c * ldq + h * Cd;
    const float* w = ew + h * Cd;
    int d = lane * 8;
    ushort4 u0 = *(const ushort4*)&qr[d];
    ushort4 u1 = *(const ushort4*)&qr[d + 4];
    float4 w0 = *(const float4*)&w[d];
    float4 w1 = *(const float4*)&w[d + 4];
    float s = b2f(u0.x) * w0.x + b2f(u0.y) * w0.y + b2f(u0.z) * w0.z + b2f(u0.w) * w0.w
            + b2f(u1.x) * w1.x + b2f(u1.y) * w1.y + b2f(u1.z) * w1.z + b2f(u1.w) * w1.w;
    #pragma unroll
    for (int o = 32; o; o >>= 1) s += __shfl_xor(s, o);
    if (lane == 0) qe[c * H + h] = s;
}

// softmax over sources r; writes bf16 alpha and aw[c,h]=sum alpha*x[r,c]
__global__ __launch_bounds__(256) void softmax_edge(
    const float* __restrict__ S, const float* __restrict__ xT,
    const float* __restrict__ qe, float* __restrict__ aw,
    unsigned short* __restrict__ ab, int H, float inv_sqrt_d)
{
    const int c = blockIdx.x, h = blockIdx.y, tid = threadIdx.x;
    const float* row = S + ((long)h * 1024 + c) * 1024;
    unsigned short* arow = ab + ((long)h * 1024 + c) * 1024;
    const float* xc = xT + (long)c * 1024;
    const float qeh = qe[c * H + h] * inv_sqrt_d;
    float l[4], xv[4];
    float mx = -1e30f;
    #pragma unroll
    for (int i = 0; i < 4; i++) {
        int r = tid + i * 256;
        xv[i] = xc[r];
        l[i] = row[r] * inv_sqrt_d + xv[i] * qeh;
        mx = fmaxf(mx, l[i]);
    }
    __shared__ float red[8];
    #pragma unroll
    for (int o = 32; o; o >>= 1) mx = fmaxf(mx, __shfl_xor(mx, o));
    if ((tid & 63) == 0) red[tid >> 6] = mx;
    __syncthreads();
    mx = fmaxf(fmaxf(red[0], red[1]), fmaxf(red[2], red[3]));
    __syncthreads();
    float e[4], se = 0.f, sa = 0.f;
    #pragma unroll
    for (int i = 0; i < 4; i++) {
        e[i] = __expf(l[i] - mx);
        se += e[i];
        sa += e[i] * xv[i];
    }
    #pragma unroll
    for (int o = 32; o; o >>= 1) { se += __shfl_xor(se, o); sa += __shfl_xor(sa, o); }
    if ((tid & 63) == 0) { red[tid >> 6] = se; red[4 + (tid >> 6)] = sa; }
    __syncthreads();
    se = red[0] + red[1] + red[2] + red[3];
    sa = red[4] + red[5] + red[6] + red[7];
    float inv = 1.f / se;
    #pragma unroll
    for (int i = 0; i < 4; i++) arow[tid + i * 256] = f2bf(e[i] * inv);
    if (tid == 0) aw[c * H + h] = sa * inv;
}

// out(fp32, has attn) += skip(bf16) + aw[c,h]*ew[f]
__global__ void combine2(float* __restrict__ out, const unsigned short* __restrict__ skipb,
                         int ldskip, const float* __restrict__ aw, const float* __restrict__ ew,
                         int F, int H)
{
    long idx = ((long)blockIdx.x * 256 + threadIdx.x) * 4;
    int c = (int)(idx / F), f = (int)(idx % F);
    int h = f >> 9;                       // Cd = 512 both layers
    float a = aw[c * H + h];
    ushort4 sk = *(const ushort4*)&skipb[(long)c * ldskip + f];
    float4 o = *(float4*)&out[idx];
    float4 w = *(const float4*)&ew[f];
    o.x += b2f(sk.x) + a * w.x; o.y += b2f(sk.y) + a * w.y;
    o.z += b2f(sk.z) + a * w.z; o.w += b2f(sk.w) + a * w.w;
    *(float4*)&out[idx] = o;
}

// ============================ GraphNorm =================================
__global__ void col_stats1(const float* __restrict__ X, float* __restrict__ ps,
                           float* __restrict__ ps2, int F)
{
    int f = blockIdx.x * 256 + threadIdx.x;
    int r0 = blockIdx.y * 32;
    float s = 0.f, s2 = 0.f;
    for (int r = r0; r < r0 + 32; r++) {
        float v = X[(long)r * F + f];
        s += v; s2 += v * v;
    }
    ps [(long)blockIdx.y * F + f] = s;
    ps2[(long)blockIdx.y * F + f] = s2;
}

__global__ void col_stats2(const float* __restrict__ ps, const float* __restrict__ ps2,
    const float* __restrict__ ms, float* __restrict__ msmu, float* __restrict__ rs, int F)
{
    int f = blockIdx.x * 256 + threadIdx.x;
    float s = 0.f, s2 = 0.f;
    for (int ch = 0; ch < 32; ch++) { s += ps[(long)ch * F + f]; s2 += ps2[(long)ch * F + f]; }
    float m  = s  * (1.f / 1024.f);
    float m2 = s2 * (1.f / 1024.f);
    float a = ms[f] * m;
    msmu[f] = a;
    float var = m2 - 2.f * a * m + a * a;
    rs[f] = rsqrtf(var + EPSV);
}

__global__ void gnorm_apply(float* __restrict__ X, const float* __restrict__ msmu,
    const float* __restrict__ rs, const float* __restrict__ g, const float* __restrict__ b, int F)
{
    long idx = ((long)blockIdx.x * 256 + threadIdx.x) * 4;
    int f = (int)(idx % F);
    float4 v = *(float4*)&X[idx];
    v.x = g[f+0] * (v.x - msmu[f+0]) * rs[f+0] + b[f+0];
    v.y = g[f+1] * (v.y - msmu[f+1]) * rs[f+1] + b[f+1];
    v.z = g[f+2] * (v.z - msmu[f+2]) * rs[f+2] + b[f+2];
    v.w = g[f+3] * (v.w - msmu[f+3]) * rs[f+3] + b[f+3];
    *(float4*)&X[idx] = v;
}

__global__ __launch_bounds__(256) void l2norm_rows(float* __restrict__ X, int F)
{
    const int r = blockIdx.x, tid = threadIdx.x;
    float* row = X + (long)r * F;
    float s = 0.f;
    for (int f = tid * 4; f < F; f += 1024) {
        float4 v = *(const float4*)&row[f];
        s += v.x*v.x + v.y*v.y + v.z*v.z + v.w*v.w;
    }
    __shared__ float red[4];
    #pragma unroll
    for (int o = 32; o; o >>= 1) s += __shfl_xor(s, o);
    if ((tid & 63) == 0) red[tid >> 6] = s;
    __syncthreads();
    s = red[0] + red[1] + red[2] + red[3];
    float inv = rsqrtf(s);
    for (int f = tid * 4; f < F; f += 1024) {
        float4 v = *(const float4*)&row[f];
        v.x *= inv; v.y *= inv; v.z *= inv; v.w *= inv;
        *(float4*)&row[f] = v;
    }
}

// ============================ host side =================================
typedef unsigned short u16;

static inline void launch_gemm(hipStream_t st, const u16* A, const u16* B, const float* bias,
                               void* C, int M, int N, int K, int lda, int ldb, int ldc,
                               int nz, long aH, long bH, long cH, bool outbf)
{
    dim3 g(N / 128, M / 128, nz), b(256);
    if (outbf) {
        if (bias) gemm_bt<1,1><<<g, b, 0, st>>>(A, B, bias, C, K, lda, ldb, ldc, aH, bH, cH);
        else      gemm_bt<0,1><<<g, b, 0, st>>>(A, B, bias, C, K, lda, ldb, ldc, aH, bH, cH);
    } else {
        gemm_bt<0,0><<<g, b, 0, st>>>(A, B, bias, C, K, lda, ldb, ldc, aH, bH, cH);
    }
}

extern "C" void kernel_launch(void* const* d_in, const int* in_sizes, int n_in,
                              void* d_out, int out_size, void* d_ws, size_t ws_size,
                              hipStream_t stream)
{
    const float* x    = (const float*)d_in[0];
    const float* q1w  = (const float*)d_in[1];  const float* q1b = (const float*)d_in[2];
    const float* k1w  = (const float*)d_in[3];  const float* k1b = (const float*)d_in[4];
    const float* v1w  = (const float*)d_in[5];  const float* v1b = (const float*)d_in[6];
    const float* e1w  = (const float*)d_in[7];
    const float* s1w  = (const float*)d_in[8];  const float* s1b = (const float*)d_in[9];
    const float* gn1g = (const float*)d_in[10]; const float* gn1b = (const float*)d_in[11];
    const float* gn1ms= (const float*)d_in[12];
    const float* q2w  = (const float*)d_in[13]; const float* q2b = (const float*)d_in[14];
    const float* k2w  = (const float*)d_in[15]; const float* k2b = (const float*)d_in[16];
    const float* v2w  = (const float*)d_in[17]; const float* v2b = (const float*)d_in[18];
    const float* e2w  = (const float*)d_in[19];
    const float* s2w  = (const float*)d_in[20]; const float* s2b = (const float*)d_in[21];
    const float* gn2g = (const float*)d_in[22]; const float* gn2b = (const float*)d_in[23];
    const float* gn2ms= (const float*)d_in[24];
    float* out = (float*)d_out;

    // workspace layout (byte offsets); peak ~107 MB
    char* W = (char*)d_ws;
    float* xT    = (float*)W;               W += (long)1024 * 1024 * 4;      // 4 MB
    u16*   xb    = (u16*)W;                 W += (long)1024 * 1024 * 2;      // 2 MB
    float* h1    = (float*)W;               W += (long)1024 * 2048 * 4;      // 8 MB
    u16*   h1b   = (u16*)W;                 W += (long)1024 * 2048 * 2;      // 4 MB
    u16*   projC = (u16*)W;                 W += (long)1024 * 16384 * 2;     // 32 MB
    char*  R     = W;                       W += (long)8192 * 2048 * 2;      // 32 MB (WT | S)
    u16*   WT    = (u16*)R;
    float* S     = (float*)R;
    u16*   ab    = (u16*)W;                 W += (long)8 * 1024 * 1024 * 2;  // 16 MB
    u16*   VT    = (u16*)W;                 W += (long)8 * 512 * 1024 * 2;   // 8 MB
    float* bc    = (float*)W;               W += 16384 * 4;
    float* qe    = (float*)W;               W += 8192 * 4;
    float* aw    = (float*)W;               W += 8192 * 4;
    float* ps    = (float*)W;               W += (long)32 * 4096 * 4;
    float* ps2   = (float*)W;               W += (long)32 * 4096 * 4;
    float* msmu  = (float*)W;               W += 4096 * 4;
    float* rs    = (float*)W;               W += 4096 * 4;

    const float isd = 1.0f / sqrtf(512.0f);

    transpose1024<<<dim3(32, 32), dim3(32, 8), 0, stream>>>(x, xT);
    f2b_kernel<<<512, 256, 0, stream>>>(x, xb);

    // ---------------- Layer 1: H=4, Cd=512, Fin=1024, F=2048 ----------------
    {
        const int F = 2048, K = 1024, H = 4;
        // weights -> WT [8192][1024] bf16 (q,k,v,s stacked along rows)
        transpose_f2b<<<dim3(64, 32), dim3(32, 8), 0, stream>>>(q1w, WT + (long)0 * F * K, F, K);
        transpose_f2b<<<dim3(64, 32), dim3(32, 8), 0, stream>>>(k1w, WT + (long)1 * F * K, F, K);
        transpose_f2b<<<dim3(64, 32), dim3(32, 8), 0, stream>>>(v1w, WT + (long)2 * F * K, F, K);
        transpose_f2b<<<dim3(64, 32), dim3(32, 8), 0, stream>>>(s1w, WT + (long)3 * F * K, F, K);
        concat4<<<32, 256, 0, stream>>>(q1b, k1b, v1b, s1b, bc, F);
        // fused projection: [1024, 8192] bf16 out (q|k|v|skip)
        launch_gemm(stream, xb, WT, bc, projC, 1024, 4 * F, K, K, K, 4 * F, 1, 0, 0, 0, true);

        compute_qe_b<<<1024, 256, 0, stream>>>(projC, e1w, qe, H, 512, 4 * F);
        // QK^T per head -> S fp32
        launch_gemm(stream, projC, projC + F, nullptr, S, 1024, 1024, 512,
                    4 * F, 4 * F, 1024, H, 512, 512, (long)1024 * 1024, false);
        softmax_edge<<<dim3(1024, H), 256, 0, stream>>>(S, xT, qe, aw, ab, H, isd);
        transpose_b2b<<<dim3(16, 32, H), dim3(32, 8), 0, stream>>>(projC + 2 * F, VT, 4 * F, 512);
        // PV -> h1 fp32
        launch_gemm(stream, ab, VT, nullptr, h1, 1024, 512, 1024,
                    1024, 1024, F, H, (long)1024 * 1024, (long)512 * 1024, 512, false);
        combine2<<<2048, 256, 0, stream>>>(h1, projC + 3 * F, 4 * F, aw, e1w, F, H);

        col_stats1<<<dim3(F / 256, 32), 256, 0, stream>>>(h1, ps, ps2, F);
        col_stats2<<<F / 256, 256, 0, stream>>>(ps, ps2, gn1ms, msmu, rs, F);
        gnorm_apply<<<(int)((long)1024 * F / 4 / 256), 256, 0, stream>>>(h1, msmu, rs, gn1g, gn1b, F);
    }
    f2b_kernel<<<1024, 256, 0, stream>>>(h1, h1b);

    // ---------------- Layer 2: H=8, Cd=512, Fin=2048, F=4096 ----------------
    {
        const int F = 4096, K = 2048, H = 8;
        concat4<<<64, 256, 0, stream>>>(q2b, k2b, v2b, s2b, bc, F);
        // pair 1: q,k weights -> WT [8192][2048]; gemm cols [0, 8192)
        transpose_f2b<<<dim3(128, 64), dim3(32, 8), 0, stream>>>(q2w, WT + (long)0 * F * K, F, K);
        transpose_f2b<<<dim3(128, 64), dim3(32, 8), 0, stream>>>(k2w, WT + (long)1 * F * K, F, K);
        launch_gemm(stream, h1b, WT, bc, projC, 1024, 2 * F, K, K, K, 4 * F, 1, 0, 0, 0, true);
        // pair 2: v,s weights; gemm cols [8192, 16384)
        transpose_f2b<<<dim3(128, 64), dim3(32, 8), 0, stream>>>(v2w, WT + (long)0 * F * K, F, K);
        transpose_f2b<<<dim3(128, 64), dim3(32, 8), 0, stream>>>(s2w, WT + (long)1 * F * K, F, K);
        launch_gemm(stream, h1b, WT, bc + 2 * F, projC + 2 * F, 1024, 2 * F, K, K, K, 4 * F, 1, 0, 0, 0, true);

        compute_qe_b<<<2048, 256, 0, stream>>>(projC, e2w, qe, H, 512, 4 * F);
        launch_gemm(stream, projC, projC + F, nullptr, S, 1024, 1024, 512,
                    4 * F, 4 * F, 1024, H, 512, 512, (long)1024 * 1024, false);
        softmax_edge<<<dim3(1024, H), 256, 0, stream>>>(S, xT, qe, aw, ab, H, isd);
        transpose_b2b<<<dim3(16, 32, H), dim3(32, 8), 0, stream>>>(projC + 2 * F, VT, 4 * F, 512);
        launch_gemm(stream, ab, VT, nullptr, out, 1024, 512, 1024,
                    1024, 1024, F, H, (long)1024 * 1024, (long)512 * 1024, 512, false);
        combine2<<<4096, 256, 0, stream>>>(out, projC + 3 * F, 4 * F, aw, e2w, F, H);

        col_stats1<<<dim3(F / 256, 32), 256, 0, stream>>>(out, ps, ps2, F);
        col_stats2<<<F / 256, 256, 0, stream>>>(ps, ps2, gn2ms, msmu, rs, F);
        gnorm_apply<<<(int)((long)1024 * F / 4 / 256), 256, 0, stream>>>(out, msmu, rs, gn2g, gn2b, F);
    }
    l2norm_rows<<<1024, 256, 0, stream>>>(out, 4096);
}

// Round 3
// 550.376 us; speedup vs baseline: 4.1842x; 1.0642x over previous
//
#include <hip/hip_runtime.h>
#include <math.h>

#define EPSV 1e-5f

typedef __attribute__((ext_vector_type(8))) short bf16x8;
typedef __attribute__((ext_vector_type(4))) float f32x4;
typedef unsigned short u16;

__device__ __forceinline__ u16 f2bf(float f) {
    unsigned int u = __float_as_uint(f);
    return (u16)((u + 0x7fffu + ((u >> 16) & 1u)) >> 16);
}
__device__ __forceinline__ float b2f(u16 u) {
    return __uint_as_float(((unsigned int)u) << 16);
}

__device__ __forceinline__ void glds16(const u16* g, u16* l) {
    __builtin_amdgcn_global_load_lds(
        (const __attribute__((address_space(1))) void*)g,
        (__attribute__((address_space(3))) void*)l, 16, 0, 0);
}

#define BARRIER() asm volatile("s_barrier" ::: "memory")
#define VMCNT(n)  asm volatile("s_waitcnt vmcnt(" #n ")" ::: "memory")

// =============== 128x256 8-phase-style bf16 MFMA GEMM (B^T) ===============
// C[M,N] = A[M,K] * B[N,K]^T (+bias). BM=128 BN=256 BK=64, 512 thr = 8 waves
// (2M x 4N), per-wave C = 64x64 (acc[4][4] of 16x16x32 MFMA). LDS 96KB
// double-buffered; XOR-swizzled rows (both-sides: pre-swizzled global src for
// linear global_load_lds dest + swizzled ds_read). Counted vmcnt (never 0 in
// main loop), setprio around MFMA clusters, peeled tail iteration.
template<int BIAS, int OUTBF>
__global__ __launch_bounds__(512, 2) void gemm256(
    const u16* __restrict__ A, const u16* __restrict__ B,
    const float* __restrict__ bias, void* __restrict__ Cout,
    int K, int lda, int ldb, int ldc, long aH, long bH, long cH)
{
    __shared__ __align__(16) u16 As[16384];   // [2][128][64]
    __shared__ __align__(16) u16 Bs[32768];   // [2][256][64]
    const int tid = threadIdx.x;
    const int wid = tid >> 6, lane = tid & 63;
    const int wm = wid >> 2, wn = wid & 3;
    const int fr = lane & 15, g = lane >> 4;
    const int bm = blockIdx.y * 128, bn = blockIdx.x * 256;
    A += (long)blockIdx.z * aH;
    B += (long)blockIdx.z * bH;

    // ---- staging: thread covers row srow (0..63) of a 64-row chunk ----
    const int srow = tid >> 3;
    const int kx = ((tid & 7) ^ (srow & 7)) << 3;   // inverse-swizzled src k
    const u16* gA = A + (long)(bm + srow) * lda + kx;
    const u16* gB = B + (long)(bn + srow) * ldb + kx;
    u16* dA = As + (wid << 9);   // wave-uniform dest base (1KB per wave)
    u16* dB = Bs + (wid << 9);

#define STAGE_A(bufi, tt) do { const u16* s_ = gA + (long)(tt) * 64; \
    u16* d_ = dA + (bufi) * 8192; \
    glds16(s_, d_); glds16(s_ + 64L * lda, d_ + 4096); } while (0)
#define STAGE_B01(bufi, tt) do { const u16* s_ = gB + (long)(tt) * 64; \
    u16* d_ = dB + (bufi) * 16384; \
    glds16(s_, d_); glds16(s_ + 64L * ldb, d_ + 4096); } while (0)
#define STAGE_B23(bufi, tt) do { const u16* s_ = gB + (long)(tt) * 64 + 128L * ldb; \
    u16* d_ = dB + (bufi) * 16384 + 8192; \
    glds16(s_, d_); glds16(s_ + 64L * ldb, d_ + 4096); } while (0)

    // ---- fragment read addressing (swizzled) ----
    const int q0 = ((0 + g) ^ (fr & 7)) << 3;       // ks=0, shorts offset
    const int q1 = ((4 + g) ^ (fr & 7)) << 3;       // ks=1
    const u16* rdA = As + (wm * 64 + fr) * 64;
    const u16* rdB = Bs + (wn * 64 + fr) * 64;

    bf16x8 am[4][2], bnf[4][2];
    f32x4 acc[4][4];
    #pragma unroll
    for (int m = 0; m < 4; m++)
        #pragma unroll
        for (int n = 0; n < 4; n++) acc[m][n] = (f32x4){0.f, 0.f, 0.f, 0.f};

#define RD_AM(bufi) do { const u16* p_ = rdA + (bufi) * 8192; \
    am[0][0] = *(const bf16x8*)(p_ + q0);        am[0][1] = *(const bf16x8*)(p_ + q1); \
    am[1][0] = *(const bf16x8*)(p_ + 1024 + q0); am[1][1] = *(const bf16x8*)(p_ + 1024 + q1); \
    am[2][0] = *(const bf16x8*)(p_ + 2048 + q0); am[2][1] = *(const bf16x8*)(p_ + 2048 + q1); \
    am[3][0] = *(const bf16x8*)(p_ + 3072 + q0); am[3][1] = *(const bf16x8*)(p_ + 3072 + q1); } while (0)
#define RD_B01(bufi) do { const u16* p_ = rdB + (bufi) * 16384; \
    bnf[0][0] = *(const bf16x8*)(p_ + q0);        bnf[0][1] = *(const bf16x8*)(p_ + q1); \
    bnf[1][0] = *(const bf16x8*)(p_ + 1024 + q0); bnf[1][1] = *(const bf16x8*)(p_ + 1024 + q1); } while (0)
#define RD_B23(bufi) do { const u16* p_ = rdB + (bufi) * 16384; \
    bnf[2][0] = *(const bf16x8*)(p_ + 2048 + q0); bnf[2][1] = *(const bf16x8*)(p_ + 2048 + q1); \
    bnf[3][0] = *(const bf16x8*)(p_ + 3072 + q0); bnf[3][1] = *(const bf16x8*)(p_ + 3072 + q1); } while (0)

#define MFMA_L() do { __builtin_amdgcn_s_setprio(1); \
    _Pragma("unroll") for (int m_ = 0; m_ < 4; m_++) \
      _Pragma("unroll") for (int n_ = 0; n_ < 2; n_++) { \
        acc[m_][n_] = __builtin_amdgcn_mfma_f32_16x16x32_bf16(am[m_][0], bnf[n_][0], acc[m_][n_], 0, 0, 0); \
        acc[m_][n_] = __builtin_amdgcn_mfma_f32_16x16x32_bf16(am[m_][1], bnf[n_][1], acc[m_][n_], 0, 0, 0); } \
    __builtin_amdgcn_s_setprio(0); } while (0)
#define MFMA_R() do { __builtin_amdgcn_s_setprio(1); \
    _Pragma("unroll") for (int m_ = 0; m_ < 4; m_++) \
      _Pragma("unroll") for (int n_ = 2; n_ < 4; n_++) { \
        acc[m_][n_] = __builtin_amdgcn_mfma_f32_16x16x32_bf16(am[m_][0], bnf[n_][0], acc[m_][n_], 0, 0, 0); \
        acc[m_][n_] = __builtin_amdgcn_mfma_f32_16x16x32_bf16(am[m_][1], bnf[n_][1], acc[m_][n_], 0, 0, 0); } \
    __builtin_amdgcn_s_setprio(0); } while (0)

    // ---- prologue: tile0 complete + tile1 A issued ----
    STAGE_A(0, 0); STAGE_B01(0, 0); STAGE_B23(0, 0);
    STAGE_A(1, 1);
    VMCNT(2);
    BARRIER();

    const int NT = K >> 6;
    const int NITm = (NT >> 1) - 1;
    for (int it = 0; it < NITm; ++it) {
        const int t = it << 1;
        // ph1: tile t (buf0), left cols
        RD_AM(0); RD_B01(0);
        STAGE_B01(1, t + 1);
        BARRIER();
        MFMA_L();
        BARRIER();
        // ph2: tile t, right cols
        RD_B23(0);
        STAGE_B23(1, t + 1); STAGE_A(0, t + 2);
        BARRIER();
        MFMA_R();
        VMCNT(2);            // tile t+1 fully landed; leaves A(t+2)
        BARRIER();
        // ph3: tile t+1 (buf1), left
        RD_AM(1); RD_B01(1);
        STAGE_B01(0, t + 2);
        BARRIER();
        MFMA_L();
        BARRIER();
        // ph4: tile t+1, right
        RD_B23(1);
        STAGE_B23(0, t + 2); STAGE_A(1, t + 3);
        BARRIER();
        MFMA_R();
        VMCNT(2);            // tile t+2 fully landed; leaves A(t+3)
        BARRIER();
    }
    {   // tail: t = NT-2
        const int t = NT - 2;
        RD_AM(0); RD_B01(0);
        STAGE_B01(1, t + 1);
        BARRIER();
        MFMA_L();
        BARRIER();
        RD_B23(0);
        STAGE_B23(1, t + 1);
        BARRIER();
        MFMA_R();
        VMCNT(0);
        BARRIER();
        RD_AM(1); RD_B01(1);
        BARRIER();
        MFMA_L();
        BARRIER();
        RD_B23(1);
        BARRIER();
        MFMA_R();
    }

    // ---- epilogue: C/D layout col=lane&15, row=(lane>>4)*4+j ----
    const int er = g << 2;
    const int crow0 = bm + wm * 64;
    const int ccol0 = bn + wn * 64;
    if (OUTBF) {
        u16* C = (u16*)Cout + (long)blockIdx.z * cH;
        #pragma unroll
        for (int m = 0; m < 4; m++)
            #pragma unroll
            for (int n = 0; n < 4; n++) {
                int col = ccol0 + n * 16 + fr;
                float bv = BIAS ? bias[col] : 0.f;
                #pragma unroll
                for (int j = 0; j < 4; j++)
                    C[(long)(crow0 + m * 16 + er + j) * ldc + col] = f2bf(acc[m][n][j] + bv);
            }
    } else {
        float* C = (float*)Cout + (long)blockIdx.z * cH;
        #pragma unroll
        for (int m = 0; m < 4; m++)
            #pragma unroll
            for (int n = 0; n < 4; n++) {
                int col = ccol0 + n * 16 + fr;
                float bv = BIAS ? bias[col] : 0.f;
                #pragma unroll
                for (int j = 0; j < 4; j++)
                    C[(long)(crow0 + m * 16 + er + j) * ldc + col] = acc[m][n][j] + bv;
            }
    }
#undef STAGE_A
#undef STAGE_B01
#undef STAGE_B23
#undef RD_AM
#undef RD_B01
#undef RD_B23
#undef MFMA_L
#undef MFMA_R
}

// ========= 128x128 MFMA GEMM for PV with fused combine epilogue =========
// out[c, h*512+d] = (alpha_h @ V_h)[c,d] + skip_bf16[c, f] + aw[c,h]*ew[f]
__global__ __launch_bounds__(256) void gemm_pv(
    const u16* __restrict__ A, const u16* __restrict__ B,
    float* __restrict__ C, int K, int lda, int ldb,
    long aH, long bH,
    const u16* __restrict__ skipb, int ldsk,
    const float* __restrict__ aw, const float* __restrict__ ew, int H, int F)
{
    __shared__ __align__(16) u16 As[4096];
    __shared__ __align__(16) u16 Bs[4096];
    const int tid = threadIdx.x;
    const int wid = tid >> 6, lane = tid & 63;
    const int bm = blockIdx.y * 128, bn = blockIdx.x * 128;
    const int h = blockIdx.z;
    A += (long)h * aH;
    B += (long)h * bH;

    const int wr = wid >> 1, wc = wid & 1;
    const int r0 = (wid << 4) + (lane >> 2);
    const int kq = (lane & 3) << 3;
    const u16* gA0 = A + (long)(bm + r0) * lda + kq;
    const u16* gA1 = gA0 + (long)64 * lda;
    const u16* gB0 = B + (long)(bn + r0) * ldb + kq;
    const u16* gB1 = gB0 + (long)64 * ldb;
    u16* lA0 = &As[wid << 9];
    u16* lA1 = &As[(wid << 9) + 2048];
    u16* lB0 = &Bs[wid << 9];
    u16* lB1 = &Bs[(wid << 9) + 2048];

    f32x4 acc[4][4];
    #pragma unroll
    for (int m = 0; m < 4; m++)
        #pragma unroll
        for (int n = 0; n < 4; n++) acc[m][n] = (f32x4){0.f, 0.f, 0.f, 0.f};

    const int fr = lane & 15;
    const int kb = (lane >> 4) << 3;
    const u16* pA = &As[(wr * 64 + fr) * 32 + kb];
    const u16* pB = &Bs[(wc * 64 + fr) * 32 + kb];

    for (int k0 = 0; k0 < K; k0 += 32) {
        glds16(gA0 + k0, lA0);
        glds16(gA1 + k0, lA1);
        glds16(gB0 + k0, lB0);
        glds16(gB1 + k0, lB1);
        __syncthreads();
        bf16x8 af[4], bf[4];
        #pragma unroll
        for (int m = 0; m < 4; m++) af[m] = *(const bf16x8*)(pA + (m << 9));
        #pragma unroll
        for (int n = 0; n < 4; n++) bf[n] = *(const bf16x8*)(pB + (n << 9));
        #pragma unroll
        for (int m = 0; m < 4; m++)
            #pragma unroll
            for (int n = 0; n < 4; n++)
                acc[m][n] = __builtin_amdgcn_mfma_f32_16x16x32_bf16(
                    af[m], bf[n], acc[m][n], 0, 0, 0);
        __syncthreads();
    }

    const int er = (lane >> 4) << 2;
    const int ec = lane & 15;
    #pragma unroll
    for (int m = 0; m < 4; m++)
        #pragma unroll
        for (int n = 0; n < 4; n++) {
            int colh = bn + wc * 64 + n * 16 + ec;   // 0..511 within head
            int f = h * 512 + colh;
            float ewf = ew[f];
            #pragma unroll
            for (int j = 0; j < 4; j++) {
                int row = bm + wr * 64 + m * 16 + er + j;
                float v = acc[m][n][j]
                        + b2f(skipb[(long)row * ldsk + f])
                        + aw[row * H + h] * ewf;
                C[(long)row * F + f] = v;
            }
        }
}

// ============================ conversions ===============================
__global__ void f2b_kernel(const float* __restrict__ src, u16* __restrict__ dst)
{
    long i = ((long)blockIdx.x * 256 + threadIdx.x) * 8;
    float4 a = *(const float4*)&src[i];
    float4 b = *(const float4*)&src[i + 4];
    u16 o[8] = { f2bf(a.x), f2bf(a.y), f2bf(a.z), f2bf(a.w),
                 f2bf(b.x), f2bf(b.y), f2bf(b.z), f2bf(b.w) };
    *(uint4*)&dst[i] = *(uint4*)o;
}

// src fp32 [K][F] (ld=ldsrc) -> dst bf16 [F][Kdim]
__global__ void transpose_f2b(const float* __restrict__ src, u16* __restrict__ dst,
                              int ldsrc, int Kdim)
{
    __shared__ float t[32][33];
    int f0 = blockIdx.x * 32, k0 = blockIdx.y * 32;
    int tx = threadIdx.x, ty = threadIdx.y;
    #pragma unroll
    for (int i = 0; i < 4; i++)
        t[ty + i * 8][tx] = src[(long)(k0 + ty + i * 8) * ldsrc + f0 + tx];
    __syncthreads();
    #pragma unroll
    for (int i = 0; i < 4; i++)
        dst[(long)(f0 + ty + i * 8) * Kdim + k0 + tx] = f2bf(t[tx][ty + i * 8]);
}

// V block (bf16, strided) -> VT per head: dst[h*512*1024 + d*1024 + r]
__global__ void transpose_b2b(const u16* __restrict__ src,
                              u16* __restrict__ dst, int ldsrc, int Cd)
{
    __shared__ u16 t[32][33];
    int h = blockIdx.z;
    int d0 = blockIdx.x * 32, r0 = blockIdx.y * 32;
    int tx = threadIdx.x, ty = threadIdx.y;
    #pragma unroll
    for (int i = 0; i < 4; i++)
        t[ty + i * 8][tx] = src[(long)(r0 + ty + i * 8) * ldsrc + h * Cd + d0 + tx];
    __syncthreads();
    #pragma unroll
    for (int i = 0; i < 4; i++)
        dst[(long)h * Cd * 1024 + (long)(d0 + ty + i * 8) * 1024 + r0 + tx] = t[tx][ty + i * 8];
}

__global__ void concat4(const float* __restrict__ a, const float* __restrict__ b,
                        const float* __restrict__ c, const float* __restrict__ d,
                        float* __restrict__ o, int F)
{
    int i = blockIdx.x * 256 + threadIdx.x;
    const float* s = (i < F) ? a : (i < 2 * F) ? b : (i < 3 * F) ? c : d;
    o[i] = s[i & (F - 1)];
}

__global__ void transpose1024(const float* __restrict__ in, float* __restrict__ out)
{
    __shared__ float t[32][33];
    int bx = blockIdx.x * 32, by = blockIdx.y * 32;
    #pragma unroll
    for (int i = 0; i < 32; i += 8)
        t[threadIdx.y + i][threadIdx.x] = in[(long)(by + threadIdx.y + i) * 1024 + bx + threadIdx.x];
    __syncthreads();
    #pragma unroll
    for (int i = 0; i < 32; i += 8)
        out[(long)(bx + threadIdx.y + i) * 1024 + by + threadIdx.x] = t[threadIdx.x][threadIdx.y + i];
}

// ====================== attention non-GEMM pieces =======================
__global__ __launch_bounds__(256) void compute_qe_b(
    const u16* __restrict__ q, const float* __restrict__ ew,
    float* __restrict__ qe, int H, int Cd, int ldq)
{
    int gw = (blockIdx.x * 256 + threadIdx.x) >> 6;
    int lane = threadIdx.x & 63;
    int c = gw / H, h = gw - c * H;
    const u16* qr = q + (long)c * ldq + h * Cd;
    const float* w = ew + h * Cd;
    int d = lane * 8;
    ushort4 u0 = *(const ushort4*)&qr[d];
    ushort4 u1 = *(const ushort4*)&qr[d + 4];
    float4 w0 = *(const float4*)&w[d];
    float4 w1 = *(const float4*)&w[d + 4];
    float s = b2f(u0.x) * w0.x + b2f(u0.y) * w0.y + b2f(u0.z) * w0.z + b2f(u0.w) * w0.w
            + b2f(u1.x) * w1.x + b2f(u1.y) * w1.y + b2f(u1.z) * w1.z + b2f(u1.w) * w1.w;
    #pragma unroll
    for (int o = 32; o; o >>= 1) s += __shfl_xor(s, o);
    if (lane == 0) qe[c * H + h] = s;
}

__global__ __launch_bounds__(256) void softmax_edge(
    const float* __restrict__ S, const float* __restrict__ xT,
    const float* __restrict__ qe, float* __restrict__ aw,
    u16* __restrict__ ab, int H, float inv_sqrt_d)
{
    const int c = blockIdx.x, h = blockIdx.y, tid = threadIdx.x;
    const float* row = S + ((long)h * 1024 + c) * 1024;
    u16* arow = ab + ((long)h * 1024 + c) * 1024;
    const float* xc = xT + (long)c * 1024;
    const float qeh = qe[c * H + h] * inv_sqrt_d;
    float l[4], xv[4];
    float mx = -1e30f;
    #pragma unroll
    for (int i = 0; i < 4; i++) {
        int r = tid + i * 256;
        xv[i] = xc[r];
        l[i] = row[r] * inv_sqrt_d + xv[i] * qeh;
        mx = fmaxf(mx, l[i]);
    }
    __shared__ float red[8];
    #pragma unroll
    for (int o = 32; o; o >>= 1) mx = fmaxf(mx, __shfl_xor(mx, o));
    if ((tid & 63) == 0) red[tid >> 6] = mx;
    __syncthreads();
    mx = fmaxf(fmaxf(red[0], red[1]), fmaxf(red[2], red[3]));
    __syncthreads();
    float e[4], se = 0.f, sa = 0.f;
    #pragma unroll
    for (int i = 0; i < 4; i++) {
        e[i] = __expf(l[i] - mx);
        se += e[i];
        sa += e[i] * xv[i];
    }
    #pragma unroll
    for (int o = 32; o; o >>= 1) { se += __shfl_xor(se, o); sa += __shfl_xor(sa, o); }
    if ((tid & 63) == 0) { red[tid >> 6] = se; red[4 + (tid >> 6)] = sa; }
    __syncthreads();
    se = red[0] + red[1] + red[2] + red[3];
    sa = red[4] + red[5] + red[6] + red[7];
    float inv = 1.f / se;
    #pragma unroll
    for (int i = 0; i < 4; i++) arow[tid + i * 256] = f2bf(e[i] * inv);
    if (tid == 0) aw[c * H + h] = sa * inv;
}

// ============================ GraphNorm =================================
__global__ void col_stats1(const float* __restrict__ X, float* __restrict__ ps,
                           float* __restrict__ ps2, int F)
{
    int f = blockIdx.x * 256 + threadIdx.x;
    int r0 = blockIdx.y * 32;
    float s = 0.f, s2 = 0.f;
    for (int r = r0; r < r0 + 32; r++) {
        float v = X[(long)r * F + f];
        s += v; s2 += v * v;
    }
    ps [(long)blockIdx.y * F + f] = s;
    ps2[(long)blockIdx.y * F + f] = s2;
}

__global__ void col_stats2(const float* __restrict__ ps, const float* __restrict__ ps2,
    const float* __restrict__ ms, float* __restrict__ msmu, float* __restrict__ rs, int F)
{
    int f = blockIdx.x * 256 + threadIdx.x;
    float s = 0.f, s2 = 0.f;
    for (int ch = 0; ch < 32; ch++) { s += ps[(long)ch * F + f]; s2 += ps2[(long)ch * F + f]; }
    float m  = s  * (1.f / 1024.f);
    float m2 = s2 * (1.f / 1024.f);
    float a = ms[f] * m;
    msmu[f] = a;
    float var = m2 - 2.f * a * m + a * a;
    rs[f] = rsqrtf(var + EPSV);
}

// OUTBF=1: write bf16 to Yb; else write fp32 to Yf (may alias X)
template<int OUTBF>
__global__ void gnorm_apply(const float* __restrict__ X, u16* __restrict__ Yb,
    float* __restrict__ Yf, const float* __restrict__ msmu,
    const float* __restrict__ rs, const float* __restrict__ g,
    const float* __restrict__ b, int F)
{
    long idx = ((long)blockIdx.x * 256 + threadIdx.x) * 4;
    int f = (int)(idx % F);
    float4 v = *(const float4*)&X[idx];
    v.x = g[f+0] * (v.x - msmu[f+0]) * rs[f+0] + b[f+0];
    v.y = g[f+1] * (v.y - msmu[f+1]) * rs[f+1] + b[f+1];
    v.z = g[f+2] * (v.z - msmu[f+2]) * rs[f+2] + b[f+2];
    v.w = g[f+3] * (v.w - msmu[f+3]) * rs[f+3] + b[f+3];
    if (OUTBF) {
        u16 o[4] = { f2bf(v.x), f2bf(v.y), f2bf(v.z), f2bf(v.w) };
        *(ushort4*)&Yb[idx] = *(ushort4*)o;
    } else {
        *(float4*)&Yf[idx] = v;
    }
}

__global__ __launch_bounds__(256) void l2norm_rows(float* __restrict__ X, int F)
{
    const int r = blockIdx.x, tid = threadIdx.x;
    float* row = X + (long)r * F;
    float s = 0.f;
    for (int f = tid * 4; f < F; f += 1024) {
        float4 v = *(const float4*)&row[f];
        s += v.x*v.x + v.y*v.y + v.z*v.z + v.w*v.w;
    }
    __shared__ float red[4];
    #pragma unroll
    for (int o = 32; o; o >>= 1) s += __shfl_xor(s, o);
    if ((tid & 63) == 0) red[tid >> 6] = s;
    __syncthreads();
    s = red[0] + red[1] + red[2] + red[3];
    float inv = rsqrtf(s);
    for (int f = tid * 4; f < F; f += 1024) {
        float4 v = *(const float4*)&row[f];
        v.x *= inv; v.y *= inv; v.z *= inv; v.w *= inv;
        *(float4*)&row[f] = v;
    }
}

// ============================ host side =================================
static inline void launch_g256(hipStream_t st, const u16* A, const u16* B,
                               const float* bias, void* C, int M, int N, int K,
                               int lda, int ldb, int ldc, int nz,
                               long aH, long bH, long cH, bool outbf)
{
    dim3 g(N / 256, M / 128, nz), b(512);
    if (outbf) gemm256<1,1><<<g, b, 0, st>>>(A, B, bias, C, K, lda, ldb, ldc, aH, bH, cH);
    else       gemm256<0,0><<<g, b, 0, st>>>(A, B, bias, C, K, lda, ldb, ldc, aH, bH, cH);
}

extern "C" void kernel_launch(void* const* d_in, const int* in_sizes, int n_in,
                              void* d_out, int out_size, void* d_ws, size_t ws_size,
                              hipStream_t stream)
{
    const float* x    = (const float*)d_in[0];
    const float* q1w  = (const float*)d_in[1];  const float* q1b = (const float*)d_in[2];
    const float* k1w  = (const float*)d_in[3];  const float* k1b = (const float*)d_in[4];
    const float* v1w  = (const float*)d_in[5];  const float* v1b = (const float*)d_in[6];
    const float* e1w  = (const float*)d_in[7];
    const float* s1w  = (const float*)d_in[8];  const float* s1b = (const float*)d_in[9];
    const float* gn1g = (const float*)d_in[10]; const float* gn1b = (const float*)d_in[11];
    const float* gn1ms= (const float*)d_in[12];
    const float* q2w  = (const float*)d_in[13]; const float* q2b = (const float*)d_in[14];
    const float* k2w  = (const float*)d_in[15]; const float* k2b = (const float*)d_in[16];
    const float* v2w  = (const float*)d_in[17]; const float* v2b = (const float*)d_in[18];
    const float* e2w  = (const float*)d_in[19];
    const float* s2w  = (const float*)d_in[20]; const float* s2b = (const float*)d_in[21];
    const float* gn2g = (const float*)d_in[22]; const float* gn2b = (const float*)d_in[23];
    const float* gn2ms= (const float*)d_in[24];
    float* out = (float*)d_out;

    // workspace layout; peak ~107 MB
    char* W = (char*)d_ws;
    float* xT    = (float*)W;               W += (long)1024 * 1024 * 4;      // 4 MB
    u16*   xb    = (u16*)W;                 W += (long)1024 * 1024 * 2;      // 2 MB
    float* h1    = (float*)W;               W += (long)1024 * 2048 * 4;      // 8 MB
    u16*   h1b   = (u16*)W;                 W += (long)1024 * 2048 * 2;      // 4 MB
    u16*   projC = (u16*)W;                 W += (long)1024 * 16384 * 2;     // 32 MB
    char*  R     = W;                       W += (long)8192 * 2048 * 2;      // 32 MB (WT | S alias)
    u16*   WT    = (u16*)R;
    float* S     = (float*)R;
    u16*   ab    = (u16*)W;                 W += (long)8 * 1024 * 1024 * 2;  // 16 MB
    u16*   VT    = (u16*)W;                 W += (long)8 * 512 * 1024 * 2;   // 8 MB
    float* bc    = (float*)W;               W += 16384 * 4;
    float* qe    = (float*)W;               W += 8192 * 4;
    float* aw    = (float*)W;               W += 8192 * 4;
    float* ps    = (float*)W;               W += (long)32 * 4096 * 4;
    float* ps2   = (float*)W;               W += (long)32 * 4096 * 4;
    float* msmu  = (float*)W;               W += 4096 * 4;
    float* rs    = (float*)W;               W += 4096 * 4;

    const float isd = 1.0f / sqrtf(512.0f);

    transpose1024<<<dim3(32, 32), dim3(32, 8), 0, stream>>>(x, xT);
    f2b_kernel<<<512, 256, 0, stream>>>(x, xb);

    // ---------------- Layer 1: H=4, Cd=512, Fin=1024, F=2048 ----------------
    {
        const int F = 2048, K = 1024, H = 4;
        transpose_f2b<<<dim3(64, 32), dim3(32, 8), 0, stream>>>(q1w, WT + (long)0 * F * K, F, K);
        transpose_f2b<<<dim3(64, 32), dim3(32, 8), 0, stream>>>(k1w, WT + (long)1 * F * K, F, K);
        transpose_f2b<<<dim3(64, 32), dim3(32, 8), 0, stream>>>(v1w, WT + (long)2 * F * K, F, K);
        transpose_f2b<<<dim3(64, 32), dim3(32, 8), 0, stream>>>(s1w, WT + (long)3 * F * K, F, K);
        concat4<<<32, 256, 0, stream>>>(q1b, k1b, v1b, s1b, bc, F);
        // fused projection: [1024, 8192] bf16 (q|k|v|skip)
        launch_g256(stream, xb, WT, bc, projC, 1024, 4 * F, K, K, K, 4 * F, 1, 0, 0, 0, true);

        compute_qe_b<<<1024, 256, 0, stream>>>(projC, e1w, qe, H, 512, 4 * F);
        // QK^T per head -> S fp32 (overwrites WT region; WT dead)
        launch_g256(stream, projC, projC + F, nullptr, S, 1024, 1024, 512,
                    4 * F, 4 * F, 1024, H, 512, 512, (long)1024 * 1024, false);
        softmax_edge<<<dim3(1024, H), 256, 0, stream>>>(S, xT, qe, aw, ab, H, isd);
        transpose_b2b<<<dim3(16, 32, H), dim3(32, 8), 0, stream>>>(projC + 2 * F, VT, 4 * F, 512);
        // PV + fused combine -> h1 fp32
        gemm_pv<<<dim3(4, 8, H), 256, 0, stream>>>(ab, VT, h1, 1024, 1024, 1024,
            (long)1024 * 1024, (long)512 * 1024, projC + 3 * F, 4 * F, aw, e1w, H, F);

        col_stats1<<<dim3(F / 256, 32), 256, 0, stream>>>(h1, ps, ps2, F);
        col_stats2<<<F / 256, 256, 0, stream>>>(ps, ps2, gn1ms, msmu, rs, F);
        gnorm_apply<1><<<(int)((long)1024 * F / 4 / 256), 256, 0, stream>>>(
            h1, h1b, nullptr, msmu, rs, gn1g, gn1b, F);
    }

    // ---------------- Layer 2: H=8, Cd=512, Fin=2048, F=4096 ----------------
    {
        const int F = 4096, K = 2048, H = 8;
        concat4<<<64, 256, 0, stream>>>(q2b, k2b, v2b, s2b, bc, F);
        transpose_f2b<<<dim3(128, 64), dim3(32, 8), 0, stream>>>(q2w, WT + (long)0 * F * K, F, K);
        transpose_f2b<<<dim3(128, 64), dim3(32, 8), 0, stream>>>(k2w, WT + (long)1 * F * K, F, K);
        launch_g256(stream, h1b, WT, bc, projC, 1024, 2 * F, K, K, K, 4 * F, 1, 0, 0, 0, true);
        transpose_f2b<<<dim3(128, 64), dim3(32, 8), 0, stream>>>(v2w, WT + (long)0 * F * K, F, K);
        transpose_f2b<<<dim3(128, 64), dim3(32, 8), 0, stream>>>(s2w, WT + (long)1 * F * K, F, K);
        launch_g256(stream, h1b, WT, bc + 2 * F, projC + 2 * F, 1024, 2 * F, K, K, K, 4 * F, 1, 0, 0, 0, true);

        compute_qe_b<<<2048, 256, 0, stream>>>(projC, e2w, qe, H, 512, 4 * F);
        launch_g256(stream, projC, projC + F, nullptr, S, 1024, 1024, 512,
                    4 * F, 4 * F, 1024, H, 512, 512, (long)1024 * 1024, false);
        softmax_edge<<<dim3(1024, H), 256, 0, stream>>>(S, xT, qe, aw, ab, H, isd);
        transpose_b2b<<<dim3(16, 32, H), dim3(32, 8), 0, stream>>>(projC + 2 * F, VT, 4 * F, 512);
        gemm_pv<<<dim3(4, 8, H), 256, 0, stream>>>(ab, VT, out, 1024, 1024, 1024,
            (long)1024 * 1024, (long)512 * 1024, projC + 3 * F, 4 * F, aw, e2w, H, F);

        col_stats1<<<dim3(F / 256, 32), 256, 0, stream>>>(out, ps, ps2, F);
        col_stats2<<<F / 256, 256, 0, stream>>>(ps, ps2, gn2ms, msmu, rs, F);
        gnorm_apply<0><<<(int)((long)1024 * F / 4 / 256), 256, 0, stream>>>(
            out, nullptr, out, msmu, rs, gn2g, gn2b, F);
    }
    l2norm_rows<<<1024, 256, 0, stream>>>(out, 4096);
}

// Round 4
// 472.441 us; speedup vs baseline: 4.8745x; 1.1650x over previous
//
#include <hip/hip_runtime.h>
#include <math.h>

#define EPSV 1e-5f

typedef __attribute__((ext_vector_type(8))) short bf16x8;
typedef __attribute__((ext_vector_type(4))) float f32x4;
typedef unsigned short u16;

__device__ __forceinline__ u16 f2bf(float f) {
    unsigned int u = __float_as_uint(f);
    return (u16)((u + 0x7fffu + ((u >> 16) & 1u)) >> 16);
}
__device__ __forceinline__ float b2f(u16 u) {
    return __uint_as_float(((unsigned int)u) << 16);
}

__device__ __forceinline__ void glds16(const u16* g, u16* l) {
    __builtin_amdgcn_global_load_lds(
        (const __attribute__((address_space(1))) void*)g,
        (__attribute__((address_space(3))) void*)l, 16, 0, 0);
}

#define BARRIER() asm volatile("s_barrier" ::: "memory")
#define VMCNT(n)  asm volatile("s_waitcnt vmcnt(" #n ")" ::: "memory")

// ============ 128x256 triple-buffered bf16 MFMA GEMM (B^T) ==============
// C[M,N] = A[M,K] * B[N,K]^T (+bias). BM=128 BN=256 BK=64, 512 thr = 8 waves
// (2M x 4N), wave tile 64x64 (acc[4][4] of 16x16x32). LDS 144KB TRIPLE buffer:
// stage tile t+2 during tile t, wait tile t+1 at end of t -> ~4-phase vmcnt
// distance, vmcnt(6) steady state (never 0 in main loop). XOR-swizzled rows
// (linear glds dest + inverse-swizzled global src + swizzled ds_read).
// PVEPI: head = col>>9, A += head*aH, fused skip+aw*ew epilogue (fp32 out).
template<int BIAS, int OUTBF, int PVEPI>
__global__ __launch_bounds__(512, 2) void gemm256(
    const u16* __restrict__ A, const u16* __restrict__ B,
    const float* __restrict__ bias, void* __restrict__ Cout,
    int K, int lda, int ldb, int ldc, long aH, long bH, long cH,
    const u16* __restrict__ skipb, int ldsk,
    const float* __restrict__ aw, const float* __restrict__ ew, int H)
{
    __shared__ __align__(16) u16 LB[3 * 24576];   // 3 x (A 16KB | B 32KB)
    const int tid = threadIdx.x;
    const int wid = tid >> 6, lane = tid & 63;
    const int wm = wid >> 2, wn = wid & 3;
    const int fr = lane & 15, g = lane >> 4;
    const int bm = blockIdx.y * 128, bn = blockIdx.x * 256;
    if (PVEPI) { A += (long)(bn >> 9) * aH; }
    else       { A += (long)blockIdx.z * aH; B += (long)blockIdx.z * bH; }

    // staging addressing: thread -> row srow of 64-row chunk, k-chunk (tid&7)
    const int srow = tid >> 3;
    const int kx = ((tid & 7) ^ (srow & 7)) << 3;   // inverse-swizzled src k
    const u16* gA = A + (long)(bm + srow) * lda + kx;
    const u16* gB = B + (long)(bn + srow) * ldb + kx;

#define STAGEA(dst, tt) do { const u16* s_ = gA + ((long)(tt) << 6); \
    u16* d_ = (dst) + (wid << 9); \
    glds16(s_, d_); glds16(s_ + (long)64 * lda, d_ + 4096); } while (0)
#define STAGEB(dst, tt) do { const u16* s_ = gB + ((long)(tt) << 6); \
    u16* d_ = (dst) + 8192 + (wid << 9); \
    glds16(s_, d_); \
    glds16(s_ + (long)64 * ldb, d_ + 4096); \
    glds16(s_ + (long)128 * ldb, d_ + 8192); \
    glds16(s_ + (long)192 * ldb, d_ + 12288); } while (0)

    // fragment read addressing (swizzled)
    const int q0 = ((0 + g) ^ (fr & 7)) << 3;   // k-subtile 0
    const int q1 = ((4 + g) ^ (fr & 7)) << 3;   // k-subtile 1
    bf16x8 am[4], bq[4];
    f32x4 acc[4][4];
    #pragma unroll
    for (int m = 0; m < 4; m++)
        #pragma unroll
        for (int n = 0; n < 4; n++) acc[m][n] = (f32x4){0.f, 0.f, 0.f, 0.f};

#define RD8(bp, qq) do { \
    const u16* pa_ = (bp) + ((wm << 6) + fr) * 64; \
    const u16* pb_ = (bp) + 8192 + ((wn << 6) + fr) * 64; \
    am[0] = *(const bf16x8*)(pa_ + (qq)); \
    am[1] = *(const bf16x8*)(pa_ + 1024 + (qq)); \
    am[2] = *(const bf16x8*)(pa_ + 2048 + (qq)); \
    am[3] = *(const bf16x8*)(pa_ + 3072 + (qq)); \
    bq[0] = *(const bf16x8*)(pb_ + (qq)); \
    bq[1] = *(const bf16x8*)(pb_ + 1024 + (qq)); \
    bq[2] = *(const bf16x8*)(pb_ + 2048 + (qq)); \
    bq[3] = *(const bf16x8*)(pb_ + 3072 + (qq)); } while (0)

#define MFMA16() do { __builtin_amdgcn_s_setprio(1); \
    _Pragma("unroll") for (int m_ = 0; m_ < 4; m_++) \
    _Pragma("unroll") for (int n_ = 0; n_ < 4; n_++) \
        acc[m_][n_] = __builtin_amdgcn_mfma_f32_16x16x32_bf16(am[m_], bq[n_], acc[m_][n_], 0, 0, 0); \
    __builtin_amdgcn_s_setprio(0); } while (0)

    u16* pr = LB;                 // tile t
    u16* pn = LB + 24576;         // tile t+1
    u16* ps = LB + 49152;         // stage target (t+2)

    // prologue: tiles 0,1 staged; wait tile 0
    STAGEA(pr, 0); STAGEB(pr, 0);
    STAGEA(pn, 1); STAGEB(pn, 1);
    VMCNT(6);
    BARRIER();

    const int NT = K >> 6;
    for (int t = 0; t < NT - 2; ++t) {
        // ph1 (k-subtile 0)
        RD8(pr, q0);
        STAGEA(ps, t + 2);
        BARRIER();
        MFMA16();
        BARRIER();
        // ph2 (k-subtile 1)
        RD8(pr, q1);
        STAGEB(ps, t + 2);
        VMCNT(6);          // tile t+1 landed; tile t+2's 6 stay in flight
        BARRIER();
        MFMA16();
        BARRIER();
        u16* tmp = pr; pr = pn; pn = ps; ps = tmp;
    }
    // tile NT-2 (no staging)
    RD8(pr, q0); BARRIER(); MFMA16(); BARRIER();
    RD8(pr, q1);
    VMCNT(0);              // drain tile NT-1
    BARRIER();
    MFMA16();
    // tile NT-1 (all landed; no LDS writes remain -> no barriers)
    RD8(pn, q0); MFMA16();
    RD8(pn, q1); MFMA16();

    // ---- epilogue: C/D layout col=lane&15, row=(lane>>4)*4+j ----
    const int er = g << 2;
    const int crow0 = bm + (wm << 6);
    const int ccol0 = bn + (wn << 6);
    if (PVEPI) {
        float* C = (float*)Cout;
        #pragma unroll
        for (int m = 0; m < 4; m++)
            #pragma unroll
            for (int n = 0; n < 4; n++) {
                int f = ccol0 + (n << 4) + fr;
                int h = f >> 9;
                float ewf = ew[f];
                #pragma unroll
                for (int j = 0; j < 4; j++) {
                    int row = crow0 + (m << 4) + er + j;
                    C[(long)row * ldc + f] = acc[m][n][j]
                        + b2f(skipb[(long)row * ldsk + f])
                        + aw[row * H + h] * ewf;
                }
            }
    } else if (OUTBF) {
        u16* C = (u16*)Cout + (long)blockIdx.z * cH;
        #pragma unroll
        for (int m = 0; m < 4; m++)
            #pragma unroll
            for (int n = 0; n < 4; n++) {
                int col = ccol0 + (n << 4) + fr;
                float bv = BIAS ? bias[col] : 0.f;
                #pragma unroll
                for (int j = 0; j < 4; j++)
                    C[(long)(crow0 + (m << 4) + er + j) * ldc + col] = f2bf(acc[m][n][j] + bv);
            }
    } else {
        float* C = (float*)Cout + (long)blockIdx.z * cH;
        #pragma unroll
        for (int m = 0; m < 4; m++)
            #pragma unroll
            for (int n = 0; n < 4; n++) {
                int col = ccol0 + (n << 4) + fr;
                #pragma unroll
                for (int j = 0; j < 4; j++)
                    C[(long)(crow0 + (m << 4) + er + j) * ldc + col] = acc[m][n][j];
            }
    }
#undef STAGEA
#undef STAGEB
#undef RD8
#undef MFMA16
}

// ============================ conversions ===============================
// x -> xT (fp32) and xb (bf16) in one pass
__global__ void xprep(const float* __restrict__ in, float* __restrict__ outT,
                      u16* __restrict__ outB)
{
    __shared__ float t[32][33];
    int bx = blockIdx.x * 32, by = blockIdx.y * 32;
    #pragma unroll
    for (int i = 0; i < 32; i += 8) {
        float v = in[(long)(by + threadIdx.y + i) * 1024 + bx + threadIdx.x];
        t[threadIdx.y + i][threadIdx.x] = v;
        outB[(long)(by + threadIdx.y + i) * 1024 + bx + threadIdx.x] = f2bf(v);
    }
    __syncthreads();
    #pragma unroll
    for (int i = 0; i < 32; i += 8)
        outT[(long)(bx + threadIdx.y + i) * 1024 + by + threadIdx.x] = t[threadIdx.x][threadIdx.y + i];
}

// up to 4 weights fp32 [K][F] -> bf16 [F][K], batched over blockIdx.z
__global__ void wtrans4(const float* s0, const float* s1, const float* s2, const float* s3,
                        u16* __restrict__ dst, int ldsrc, int Kdim, long dstride)
{
    int which = blockIdx.z;
    const float* src = which == 0 ? s0 : which == 1 ? s1 : which == 2 ? s2 : s3;
    dst += (long)which * dstride;
    __shared__ float t[32][33];
    int f0 = blockIdx.x * 32, k0 = blockIdx.y * 32;
    int tx = threadIdx.x, ty = threadIdx.y;
    #pragma unroll
    for (int i = 0; i < 4; i++)
        t[ty + i * 8][tx] = src[(long)(k0 + ty + i * 8) * ldsrc + f0 + tx];
    __syncthreads();
    #pragma unroll
    for (int i = 0; i < 4; i++)
        dst[(long)(f0 + ty + i * 8) * Kdim + k0 + tx] = f2bf(t[tx][ty + i * 8]);
}

// V block (bf16, strided) -> VT per head: dst[h*512*1024 + d*1024 + r]
__global__ void transpose_b2b(const u16* __restrict__ src,
                              u16* __restrict__ dst, int ldsrc, int Cd)
{
    __shared__ u16 t[32][33];
    int h = blockIdx.z;
    int d0 = blockIdx.x * 32, r0 = blockIdx.y * 32;
    int tx = threadIdx.x, ty = threadIdx.y;
    #pragma unroll
    for (int i = 0; i < 4; i++)
        t[ty + i * 8][tx] = src[(long)(r0 + ty + i * 8) * ldsrc + h * Cd + d0 + tx];
    __syncthreads();
    #pragma unroll
    for (int i = 0; i < 4; i++)
        dst[(long)h * Cd * 1024 + (long)(d0 + ty + i * 8) * 1024 + r0 + tx] = t[tx][ty + i * 8];
}

__global__ void concat4(const float* __restrict__ a, const float* __restrict__ b,
                        const float* __restrict__ c, const float* __restrict__ d,
                        float* __restrict__ o, int F)
{
    int i = blockIdx.x * 256 + threadIdx.x;
    const float* s = (i < F) ? a : (i < 2 * F) ? b : (i < 3 * F) ? c : d;
    o[i] = s[i & (F - 1)];
}

// ================== softmax with fused qe + edge term ===================
__global__ __launch_bounds__(256) void softmax_qe(
    const float* __restrict__ S, const float* __restrict__ xT,
    const u16* __restrict__ qmat, int ldq, const float* __restrict__ ew,
    float* __restrict__ aw, u16* __restrict__ ab, int H, float isd)
{
    const int c = blockIdx.x, h = blockIdx.y, tid = threadIdx.x;
    __shared__ float red[8];
    // qe[c,h] = q[c, h*512: ] . ew[h*512: ]
    const u16* qr = qmat + (long)c * ldq + (h << 9);
    const float* wv = ew + (h << 9);
    int d = tid << 1;
    float p = b2f(qr[d]) * wv[d] + b2f(qr[d + 1]) * wv[d + 1];
    #pragma unroll
    for (int o = 32; o; o >>= 1) p += __shfl_xor(p, o);
    if ((tid & 63) == 0) red[tid >> 6] = p;
    __syncthreads();
    const float qeh = (red[0] + red[1] + red[2] + red[3]) * isd;
    __syncthreads();

    const float* row = S + ((long)h * 1024 + c) * 1024;
    u16* arow = ab + ((long)h * 1024 + c) * 1024;
    const float* xc = xT + (long)c * 1024;
    float l[4], xv[4];
    float mx = -1e30f;
    #pragma unroll
    for (int i = 0; i < 4; i++) {
        int r = tid + i * 256;
        xv[i] = xc[r];
        l[i] = row[r] * isd + xv[i] * qeh;
        mx = fmaxf(mx, l[i]);
    }
    #pragma unroll
    for (int o = 32; o; o >>= 1) mx = fmaxf(mx, __shfl_xor(mx, o));
    if ((tid & 63) == 0) red[tid >> 6] = mx;
    __syncthreads();
    mx = fmaxf(fmaxf(red[0], red[1]), fmaxf(red[2], red[3]));
    __syncthreads();
    float e[4], se = 0.f, sa = 0.f;
    #pragma unroll
    for (int i = 0; i < 4; i++) {
        e[i] = __expf(l[i] - mx);
        se += e[i];
        sa += e[i] * xv[i];
    }
    #pragma unroll
    for (int o = 32; o; o >>= 1) { se += __shfl_xor(se, o); sa += __shfl_xor(sa, o); }
    if ((tid & 63) == 0) { red[tid >> 6] = se; red[4 + (tid >> 6)] = sa; }
    __syncthreads();
    se = red[0] + red[1] + red[2] + red[3];
    sa = red[4] + red[5] + red[6] + red[7];
    float inv = 1.f / se;
    #pragma unroll
    for (int i = 0; i < 4; i++) arow[tid + i * 256] = f2bf(e[i] * inv);
    if (tid == 0) aw[c * H + h] = sa * inv;
}

// ============================ GraphNorm =================================
__global__ void col_stats1(const float* __restrict__ X, float* __restrict__ ps,
                           float* __restrict__ ps2, int F)
{
    int f = blockIdx.x * 256 + threadIdx.x;
    int r0 = blockIdx.y * 32;
    float s = 0.f, s2 = 0.f;
    for (int r = r0; r < r0 + 32; r++) {
        float v = X[(long)r * F + f];
        s += v; s2 += v * v;
    }
    ps [(long)blockIdx.y * F + f] = s;
    ps2[(long)blockIdx.y * F + f] = s2;
}

__global__ void col_stats2(const float* __restrict__ ps, const float* __restrict__ ps2,
    const float* __restrict__ ms, float* __restrict__ msmu, float* __restrict__ rs, int F)
{
    int f = blockIdx.x * 256 + threadIdx.x;
    float s = 0.f, s2 = 0.f;
    for (int ch = 0; ch < 32; ch++) { s += ps[(long)ch * F + f]; s2 += ps2[(long)ch * F + f]; }
    float m  = s  * (1.f / 1024.f);
    float m2 = s2 * (1.f / 1024.f);
    float a = ms[f] * m;
    msmu[f] = a;
    float var = m2 - 2.f * a * m + a * a;
    rs[f] = rsqrtf(var + EPSV);
}

// L1: apply GraphNorm, write bf16
__global__ void gnorm_apply_b(const float* __restrict__ X, u16* __restrict__ Yb,
    const float* __restrict__ msmu, const float* __restrict__ rs,
    const float* __restrict__ g, const float* __restrict__ b, int F)
{
    long idx = ((long)blockIdx.x * 256 + threadIdx.x) * 4;
    int f = (int)(idx % F);
    float4 v = *(const float4*)&X[idx];
    v.x = g[f+0] * (v.x - msmu[f+0]) * rs[f+0] + b[f+0];
    v.y = g[f+1] * (v.y - msmu[f+1]) * rs[f+1] + b[f+1];
    v.z = g[f+2] * (v.z - msmu[f+2]) * rs[f+2] + b[f+2];
    v.w = g[f+3] * (v.w - msmu[f+3]) * rs[f+3] + b[f+3];
    u16 o[4] = { f2bf(v.x), f2bf(v.y), f2bf(v.z), f2bf(v.w) };
    *(ushort4*)&Yb[idx] = *(ushort4*)o;
}

// L2 final: GraphNorm apply + row L2-normalize, one pass (F == 4096)
__global__ __launch_bounds__(256) void gnorm_l2(
    float* __restrict__ X, const float* __restrict__ msmu,
    const float* __restrict__ rs, const float* __restrict__ g,
    const float* __restrict__ b, int F)
{
    const int r = blockIdx.x, tid = threadIdx.x;
    float* row = X + (long)r * F;
    float v[16];
    float ss = 0.f;
    #pragma unroll
    for (int i = 0; i < 4; i++) {
        int f = (tid << 2) + (i << 10);
        float4 x4 = *(const float4*)&row[f];
        float a0 = g[f+0] * (x4.x - msmu[f+0]) * rs[f+0] + b[f+0];
        float a1 = g[f+1] * (x4.y - msmu[f+1]) * rs[f+1] + b[f+1];
        float a2 = g[f+2] * (x4.z - msmu[f+2]) * rs[f+2] + b[f+2];
        float a3 = g[f+3] * (x4.w - msmu[f+3]) * rs[f+3] + b[f+3];
        v[i*4+0] = a0; v[i*4+1] = a1; v[i*4+2] = a2; v[i*4+3] = a3;
        ss += a0*a0 + a1*a1 + a2*a2 + a3*a3;
    }
    __shared__ float red[4];
    #pragma unroll
    for (int o = 32; o; o >>= 1) ss += __shfl_xor(ss, o);
    if ((tid & 63) == 0) red[tid >> 6] = ss;
    __syncthreads();
    ss = red[0] + red[1] + red[2] + red[3];
    float inv = rsqrtf(ss);
    #pragma unroll
    for (int i = 0; i < 4; i++) {
        int f = (tid << 2) + (i << 10);
        float4 o4;
        o4.x = v[i*4+0] * inv; o4.y = v[i*4+1] * inv;
        o4.z = v[i*4+2] * inv; o4.w = v[i*4+3] * inv;
        *(float4*)&row[f] = o4;
    }
}

// ============================ host side =================================
static inline void g256_proj(hipStream_t st, const u16* A, const u16* B, const float* bias,
                             u16* C, int M, int N, int K, int lda, int ldb, int ldc)
{
    dim3 gr(N / 256, M / 128, 1), bl(512);
    gemm256<1,1,0><<<gr, bl, 0, st>>>(A, B, bias, C, K, lda, ldb, ldc, 0, 0, 0,
                                      nullptr, 0, nullptr, nullptr, 0);
}
static inline void g256_qk(hipStream_t st, const u16* A, const u16* B, float* C,
                           int K, int lda, int ldb, int H)
{
    dim3 gr(1024 / 256, 1024 / 128, H), bl(512);
    gemm256<0,0,0><<<gr, bl, 0, st>>>(A, B, nullptr, C, K, lda, ldb, 1024,
                                      512, 512, (long)1024 * 1024,
                                      nullptr, 0, nullptr, nullptr, 0);
}
static inline void g256_pv(hipStream_t st, const u16* A, const u16* B, float* C,
                           int H, int F, const u16* skipb, int ldsk,
                           const float* aw, const float* ew)
{
    dim3 gr((H * 512) / 256, 1024 / 128, 1), bl(512);
    gemm256<0,0,1><<<gr, bl, 0, st>>>(A, B, nullptr, C, 1024, 1024, 1024, F,
                                      (long)1024 * 1024, 0, 0,
                                      skipb, ldsk, aw, ew, H);
}

extern "C" void kernel_launch(void* const* d_in, const int* in_sizes, int n_in,
                              void* d_out, int out_size, void* d_ws, size_t ws_size,
                              hipStream_t stream)
{
    const float* x    = (const float*)d_in[0];
    const float* q1w  = (const float*)d_in[1];  const float* q1b = (const float*)d_in[2];
    const float* k1w  = (const float*)d_in[3];  const float* k1b = (const float*)d_in[4];
    const float* v1w  = (const float*)d_in[5];  const float* v1b = (const float*)d_in[6];
    const float* e1w  = (const float*)d_in[7];
    const float* s1w  = (const float*)d_in[8];  const float* s1b = (const float*)d_in[9];
    const float* gn1g = (const float*)d_in[10]; const float* gn1b = (const float*)d_in[11];
    const float* gn1ms= (const float*)d_in[12];
    const float* q2w  = (const float*)d_in[13]; const float* q2b = (const float*)d_in[14];
    const float* k2w  = (const float*)d_in[15]; const float* k2b = (const float*)d_in[16];
    const float* v2w  = (const float*)d_in[17]; const float* v2b = (const float*)d_in[18];
    const float* e2w  = (const float*)d_in[19];
    const float* s2w  = (const float*)d_in[20]; const float* s2b = (const float*)d_in[21];
    const float* gn2g = (const float*)d_in[22]; const float* gn2b = (const float*)d_in[23];
    const float* gn2ms= (const float*)d_in[24];
    float* out = (float*)d_out;

    // workspace layout; peak ~107 MB
    char* W = (char*)d_ws;
    float* xT    = (float*)W;               W += (long)1024 * 1024 * 4;      // 4 MB
    u16*   xb    = (u16*)W;                 W += (long)1024 * 1024 * 2;      // 2 MB
    float* h1    = (float*)W;               W += (long)1024 * 2048 * 4;      // 8 MB
    u16*   h1b   = (u16*)W;                 W += (long)1024 * 2048 * 2;      // 4 MB
    u16*   projC = (u16*)W;                 W += (long)1024 * 16384 * 2;     // 32 MB
    char*  R     = W;                       W += (long)8192 * 2048 * 2;      // 32 MB (WT | S alias)
    u16*   WT    = (u16*)R;
    float* S     = (float*)R;
    u16*   ab    = (u16*)W;                 W += (long)8 * 1024 * 1024 * 2;  // 16 MB
    u16*   VT    = (u16*)W;                 W += (long)8 * 512 * 1024 * 2;   // 8 MB
    float* bc    = (float*)W;               W += 16384 * 4;
    float* aw    = (float*)W;               W += 8192 * 4;
    float* ps    = (float*)W;               W += (long)32 * 4096 * 4;
    float* ps2   = (float*)W;               W += (long)32 * 4096 * 4;
    float* msmu  = (float*)W;               W += 4096 * 4;
    float* rs    = (float*)W;               W += 4096 * 4;

    const float isd = 1.0f / sqrtf(512.0f);

    xprep<<<dim3(32, 32), dim3(32, 8), 0, stream>>>(x, xT, xb);

    // ---------------- Layer 1: H=4, Cd=512, Fin=1024, F=2048 ----------------
    {
        const int F = 2048, K = 1024, H = 4;
        wtrans4<<<dim3(64, 32, 4), dim3(32, 8), 0, stream>>>(
            q1w, k1w, v1w, s1w, WT, F, K, (long)F * K);
        concat4<<<32, 256, 0, stream>>>(q1b, k1b, v1b, s1b, bc, F);
        // fused projection: [1024, 8192] bf16 (q|k|v|skip)
        g256_proj(stream, xb, WT, bc, projC, 1024, 4 * F, K, K, K, 4 * F);
        // QK^T per head -> S fp32 (overwrites WT; WT dead)
        g256_qk(stream, projC, projC + F, S, 512, 4 * F, 4 * F, H);
        softmax_qe<<<dim3(1024, H), 256, 0, stream>>>(S, xT, projC, 4 * F, e1w, aw, ab, H, isd);
        transpose_b2b<<<dim3(16, 32, H), dim3(32, 8), 0, stream>>>(projC + 2 * F, VT, 4 * F, 512);
        // PV (all heads, one launch) + fused skip+edge epilogue -> h1 fp32
        g256_pv(stream, ab, VT, h1, H, F, projC + 3 * F, 4 * F, aw, e1w);

        col_stats1<<<dim3(F / 256, 32), 256, 0, stream>>>(h1, ps, ps2, F);
        col_stats2<<<F / 256, 256, 0, stream>>>(ps, ps2, gn1ms, msmu, rs, F);
        gnorm_apply_b<<<(int)((long)1024 * F / 4 / 256), 256, 0, stream>>>(
            h1, h1b, msmu, rs, gn1g, gn1b, F);
    }

    // ---------------- Layer 2: H=8, Cd=512, Fin=2048, F=4096 ----------------
    {
        const int F = 4096, K = 2048, H = 8;
        concat4<<<64, 256, 0, stream>>>(q2b, k2b, v2b, s2b, bc, F);
        wtrans4<<<dim3(128, 64, 2), dim3(32, 8), 0, stream>>>(
            q2w, k2w, nullptr, nullptr, WT, F, K, (long)F * K);
        g256_proj(stream, h1b, WT, bc, projC, 1024, 2 * F, K, K, K, 4 * F);
        wtrans4<<<dim3(128, 64, 2), dim3(32, 8), 0, stream>>>(
            v2w, s2w, nullptr, nullptr, WT, F, K, (long)F * K);
        g256_proj(stream, h1b, WT, bc + 2 * F, projC + 2 * F, 1024, 2 * F, K, K, K, 4 * F);

        g256_qk(stream, projC, projC + F, S, 512, 4 * F, 4 * F, H);
        softmax_qe<<<dim3(1024, H), 256, 0, stream>>>(S, xT, projC, 4 * F, e2w, aw, ab, H, isd);
        transpose_b2b<<<dim3(16, 32, H), dim3(32, 8), 0, stream>>>(projC + 2 * F, VT, 4 * F, 512);
        g256_pv(stream, ab, VT, out, H, F, projC + 3 * F, 4 * F, aw, e2w);

        col_stats1<<<dim3(F / 256, 32), 256, 0, stream>>>(out, ps, ps2, F);
        col_stats2<<<F / 256, 256, 0, stream>>>(ps, ps2, gn2ms, msmu, rs, F);
        gnorm_l2<<<1024, 256, 0, stream>>>(out, msmu, rs, gn2g, gn2b, F);
    }
}